// Round 10
// baseline (360.899 us; speedup 1.0000x reference)
//
#include <hip/hip_runtime.h>
#include <math.h>

// ---------------------------------------------------------------------------
// GATNet (3x GATConv + final linear + MLP), MI355X.
// R9: agg v7 — 32-edge batches with 8 independent gathers in flight (4x MLP);
// gat_scores fused into GEMM epilogues (fp32-acc scores, -3 dispatches).
// Carried: MFMA GEMMs, alpha v2, L2-sliced groups, all-bf16, fused head.
// ---------------------------------------------------------------------------

typedef unsigned short bf16_t;
typedef __attribute__((ext_vector_type(8))) short bf16x8;
typedef __attribute__((ext_vector_type(4))) float f32x4;

__device__ inline float bf2f(bf16_t u) {
    union { unsigned int i; float f; } v; v.i = ((unsigned int)u) << 16; return v.f;
}
__device__ inline float u2f(unsigned int x) {
    union { unsigned int i; float f; } v; v.i = x; return v.f;
}
__device__ inline bf16_t f2bf(float f) {
    union { float f; unsigned int i; } v; v.f = f;
    unsigned int r = v.i + 0x7FFF + ((v.i >> 16) & 1);   // round-nearest-even
    return (bf16_t)(r >> 16);
}

// ------------------------------ CSR build ----------------------------------

__global__ void zero_i32(int* p, int n) {
    int i = blockIdx.x * blockDim.x + threadIdx.x;
    if (i < n) p[i] = 0;
}

__global__ void count_edges(const int* __restrict__ ei, int E, int Nn,
                            int* __restrict__ counts) {
    int e = blockIdx.x * blockDim.x + threadIdx.x;
    if (e >= E + Nn) return;
    int dst = (e < E) ? ei[E + e] : (e - E);   // self-loops appended
    atomicAdd(&counts[dst], 1);
}

// single block, 1024 threads: serial-per-thread + shuffle block scan
__global__ __launch_bounds__(1024) void scan_rowptr(const int* __restrict__ counts,
                                                    int* __restrict__ rowptr, int n) {
    const int IPT = (n + 1023) / 1024;   // <=16
    int t = threadIdx.x;
    int base = t * IPT;
    int loc[16];
    int run = 0;
#pragma unroll
    for (int i = 0; i < 16; i++) {
        if (i >= IPT) break;
        int idx = base + i;
        int v = (idx < n) ? counts[idx] : 0;
        loc[i] = run;
        run += v;
    }
    int lane = t & 63, wid = t >> 6;
    int v = run;
    for (int off = 1; off < 64; off <<= 1) {
        int u = __shfl_up(v, off, 64);
        if (lane >= off) v += u;
    }
    __shared__ int wsum[16];
    __shared__ int woff[16];
    if (lane == 63) wsum[wid] = v;
    __syncthreads();
    if (t == 0) { int s = 0; for (int i = 0; i < 16; i++) { woff[i] = s; s += wsum[i]; } }
    __syncthreads();
    int excl = v - run + woff[wid];
#pragma unroll
    for (int i = 0; i < 16; i++) {
        if (i >= IPT) break;
        int idx = base + i;
        if (idx < n) rowptr[idx] = excl + loc[i];
    }
    if (t == 1023) rowptr[n] = excl + run;
}

__global__ void fill_edges(const int* __restrict__ ei, int E, int Nn,
                           const int* __restrict__ rowptr, int* __restrict__ cursor,
                           int* __restrict__ edge_src) {
    int e = blockIdx.x * blockDim.x + threadIdx.x;
    if (e >= E + Nn) return;
    int src, dst;
    if (e < E) { src = ei[e]; dst = ei[E + e]; }
    else       { src = e - E; dst = src; }
    int pos = atomicAdd(&cursor[dst], 1);
    edge_src[rowptr[dst] + pos] = src;
}

// ---------------------------------------------------------------------------
// Fused transpose+cast for both weight matrices (K=256 each).
// ---------------------------------------------------------------------------
__global__ __launch_bounds__(256) void transpose_cast2(const float* __restrict__ W2,
                                                       bf16_t* __restrict__ Wt2,
                                                       const float* __restrict__ W3,
                                                       bf16_t* __restrict__ Wt3) {
    __shared__ float tile[16][17];
    const float* W; bf16_t* Wt; int Nc, n0;
    if (blockIdx.y < 16) { W = W2; Wt = Wt2; Nc = 256; n0 = blockIdx.y * 16; }
    else                 { W = W3; Wt = Wt3; Nc = 768; n0 = (blockIdx.y - 16) * 16; }
    int k0 = blockIdx.x * 16;
    int tx = threadIdx.x & 15, ty = threadIdx.x >> 4;
    tile[ty][tx] = W[(size_t)(k0 + ty) * Nc + n0 + tx];
    __syncthreads();
    Wt[(size_t)(n0 + ty) * 256 + k0 + tx] = f2bf(tile[tx][ty]);
}

// ---------------------------------------------------------------------------
// fp32 GEMM (layer 1, K=16, C=32, H=8), bf16 out + fused al/ar scores.
// Block covers 64 cols = 2 heads; per-row head scores reduced over tx lanes.
// ---------------------------------------------------------------------------
__global__ __launch_bounds__(256) void gemm_f32_sc(const float* __restrict__ A,
                                                   const float* __restrict__ B,
                                                   bf16_t* __restrict__ Cm,
                                                   const float* __restrict__ a_s,
                                                   const float* __restrict__ a_d,
                                                   float* __restrict__ al,
                                                   float* __restrict__ ar,
                                                   int M, int K, int Nc, int H) {
    __shared__ float As[16][64];
    __shared__ float Bs[16][64];
    int t  = threadIdx.x;
    int tx = t & 15, ty = t >> 4;
    int row0 = blockIdx.y * 64, col0 = blockIdx.x * 64;
    int a_r = t >> 2, a_c = (t & 3) * 4;
    int b_r = t >> 4, b_c = (t & 15) * 4;

    float acc[4][4];
#pragma unroll
    for (int i = 0; i < 4; i++)
#pragma unroll
        for (int j = 0; j < 4; j++) acc[i][j] = 0.f;

    for (int kt = 0; kt < K; kt += 16) {
        float4 av = make_float4(0.f, 0.f, 0.f, 0.f);
        int gr = row0 + a_r;
        if (gr < M) av = *(const float4*)(A + (size_t)gr * K + kt + a_c);
        As[a_c + 0][a_r] = av.x;
        As[a_c + 1][a_r] = av.y;
        As[a_c + 2][a_r] = av.z;
        As[a_c + 3][a_r] = av.w;
        float4 bv = *(const float4*)(B + (size_t)(kt + b_r) * Nc + col0 + b_c);
        *(float4*)&Bs[b_r][b_c] = bv;
        __syncthreads();
#pragma unroll
        for (int k = 0; k < 16; k++) {
            float4 a4 = *(const float4*)&As[k][ty * 4];
            float4 b4 = *(const float4*)&Bs[k][tx * 4];
            float aa[4] = {a4.x, a4.y, a4.z, a4.w};
            float bb[4] = {b4.x, b4.y, b4.z, b4.w};
#pragma unroll
            for (int i = 0; i < 4; i++)
#pragma unroll
                for (int j = 0; j < 4; j++) acc[i][j] += aa[i] * bb[j];
        }
        __syncthreads();
    }
    float4 asv = *(const float4*)(a_s + col0 + tx * 4);
    float4 adv = *(const float4*)(a_d + col0 + tx * 4);
#pragma unroll
    for (int i = 0; i < 4; i++) {
        int gr = row0 + ty * 4 + i;
        // scores: this thread's 4 cols lie in one head (tx<8 -> head A else B)
        float sa = acc[i][0] * asv.x + acc[i][1] * asv.y + acc[i][2] * asv.z + acc[i][3] * asv.w;
        float sd = acc[i][0] * adv.x + acc[i][1] * adv.y + acc[i][2] * adv.z + acc[i][3] * adv.w;
#pragma unroll
        for (int off = 4; off > 0; off >>= 1) {
            sa += __shfl_xor(sa, off, 64);
            sd += __shfl_xor(sd, off, 64);
        }
        if ((tx == 0 || tx == 8) && gr < M) {
            int h = (col0 >> 5) + (tx >> 3);
            al[gr * H + h] = sa;
            ar[gr * H + h] = sd;
        }
        if (gr < M) {
            ushort4 v;
            v.x = f2bf(acc[i][0]); v.y = f2bf(acc[i][1]);
            v.z = f2bf(acc[i][2]); v.w = f2bf(acc[i][3]);
            *(ushort4*)(Cm + (size_t)gr * Nc + col0 + tx * 4) = v;
        }
    }
}

// ---------------------------------------------------------------------------
// MFMA bf16 GEMM (layers 2/3) + fused al/ar scores.  C_ = head width (32|64);
// block col-width 64 is a multiple of C_, so scores are block-local (no
// atomics): per row, reduce acc*a_s over the 16 l16 lanes (shfl_xor 1/2/4/8).
// ---------------------------------------------------------------------------
template <int C_>
__global__ __launch_bounds__(256) void gemm_mfma_sc(const bf16_t* __restrict__ A,
                                                    const bf16_t* __restrict__ Bt,
                                                    bf16_t* __restrict__ Cm,
                                                    const float* __restrict__ a_s,
                                                    const float* __restrict__ a_d,
                                                    float* __restrict__ al,
                                                    float* __restrict__ ar,
                                                    int M, int K, int Nc, int H) {
    int wave = threadIdx.x >> 6, lane = threadIdx.x & 63;
    int quad = lane >> 4, l16 = lane & 15;
    int m0 = blockIdx.y * 128 + wave * 32;
    int n0 = blockIdx.x * 64;

    f32x4 acc[2][4];
    f32x4 z = {0.f, 0.f, 0.f, 0.f};
#pragma unroll
    for (int i = 0; i < 2; i++)
#pragma unroll
        for (int j = 0; j < 4; j++) acc[i][j] = z;

    int r0 = m0 + l16;       if (r0 >= M) r0 = M - 1;
    int r1 = m0 + 16 + l16;  if (r1 >= M) r1 = M - 1;
    const bf16_t* Ap0 = A + (size_t)r0 * K + quad * 8;
    const bf16_t* Ap1 = A + (size_t)r1 * K + quad * 8;
    const bf16_t* Bp0 = Bt + (size_t)(n0 + 0  + l16) * K + quad * 8;
    const bf16_t* Bp1 = Bt + (size_t)(n0 + 16 + l16) * K + quad * 8;
    const bf16_t* Bp2 = Bt + (size_t)(n0 + 32 + l16) * K + quad * 8;
    const bf16_t* Bp3 = Bt + (size_t)(n0 + 48 + l16) * K + quad * 8;

    for (int kt = 0; kt < K; kt += 32) {
        bf16x8 a0 = *(const bf16x8*)(Ap0 + kt);
        bf16x8 a1 = *(const bf16x8*)(Ap1 + kt);
        bf16x8 b0 = *(const bf16x8*)(Bp0 + kt);
        bf16x8 b1 = *(const bf16x8*)(Bp1 + kt);
        bf16x8 b2 = *(const bf16x8*)(Bp2 + kt);
        bf16x8 b3 = *(const bf16x8*)(Bp3 + kt);
        acc[0][0] = __builtin_amdgcn_mfma_f32_16x16x32_bf16(a0, b0, acc[0][0], 0, 0, 0);
        acc[1][0] = __builtin_amdgcn_mfma_f32_16x16x32_bf16(a1, b0, acc[1][0], 0, 0, 0);
        acc[0][1] = __builtin_amdgcn_mfma_f32_16x16x32_bf16(a0, b1, acc[0][1], 0, 0, 0);
        acc[1][1] = __builtin_amdgcn_mfma_f32_16x16x32_bf16(a1, b1, acc[1][1], 0, 0, 0);
        acc[0][2] = __builtin_amdgcn_mfma_f32_16x16x32_bf16(a0, b2, acc[0][2], 0, 0, 0);
        acc[1][2] = __builtin_amdgcn_mfma_f32_16x16x32_bf16(a1, b2, acc[1][2], 0, 0, 0);
        acc[0][3] = __builtin_amdgcn_mfma_f32_16x16x32_bf16(a0, b3, acc[0][3], 0, 0, 0);
        acc[1][3] = __builtin_amdgcn_mfma_f32_16x16x32_bf16(a1, b3, acc[1][3], 0, 0, 0);
    }

    float asv[4], adv[4];
#pragma unroll
    for (int j = 0; j < 4; j++) {
        asv[j] = a_s[n0 + j * 16 + l16];
        adv[j] = a_d[n0 + j * 16 + l16];
    }
#pragma unroll
    for (int i = 0; i < 2; i++)
#pragma unroll
        for (int r = 0; r < 4; r++) {
            int gr = m0 + i * 16 + quad * 4 + r;
            if (C_ == 64) {
                float sa = acc[i][0][r] * asv[0] + acc[i][1][r] * asv[1]
                         + acc[i][2][r] * asv[2] + acc[i][3][r] * asv[3];
                float sd = acc[i][0][r] * adv[0] + acc[i][1][r] * adv[1]
                         + acc[i][2][r] * adv[2] + acc[i][3][r] * adv[3];
#pragma unroll
                for (int off = 8; off > 0; off >>= 1) {
                    sa += __shfl_xor(sa, off, 64);
                    sd += __shfl_xor(sd, off, 64);
                }
                if (l16 == 0 && gr < M) {
                    int h = n0 >> 6;
                    al[gr * H + h] = sa;
                    ar[gr * H + h] = sd;
                }
            } else {
                float saA = acc[i][0][r] * asv[0] + acc[i][1][r] * asv[1];
                float saB = acc[i][2][r] * asv[2] + acc[i][3][r] * asv[3];
                float sdA = acc[i][0][r] * adv[0] + acc[i][1][r] * adv[1];
                float sdB = acc[i][2][r] * adv[2] + acc[i][3][r] * adv[3];
#pragma unroll
                for (int off = 8; off > 0; off >>= 1) {
                    saA += __shfl_xor(saA, off, 64);
                    saB += __shfl_xor(saB, off, 64);
                    sdA += __shfl_xor(sdA, off, 64);
                    sdB += __shfl_xor(sdB, off, 64);
                }
                if (l16 == 0 && gr < M) {
                    int h = n0 >> 5;
                    al[gr * H + h]     = saA;
                    ar[gr * H + h]     = sdA;
                    al[gr * H + h + 1] = saB;
                    ar[gr * H + h + 1] = sdB;
                }
            }
        }
#pragma unroll
    for (int i = 0; i < 2; i++)
#pragma unroll
        for (int j = 0; j < 4; j++)
#pragma unroll
            for (int r = 0; r < 4; r++) {
                int gr = m0 + i * 16 + quad * 4 + r;
                if (gr < M) Cm[(size_t)gr * Nc + n0 + j * 16 + l16] = f2bf(acc[i][j][r]);
            }
}

// ---------------------------------------------------------------------------
// alpha v2: wave per node, ALL heads; row-contiguous al reads; register p
// for deg<=128, guarded tail beyond; per-head shuffle reduce; planar stores.
// ---------------------------------------------------------------------------
template <int H>
__global__ __launch_bounds__(256) void alpha_node(const float* __restrict__ al,
                                                  const float* __restrict__ ar,
                                                  const int* __restrict__ rowptr,
                                                  const int* __restrict__ esrc,
                                                  float* __restrict__ alpha,
                                                  int n, int Etot) {
    int node = (blockIdx.x * blockDim.x + threadIdx.x) >> 6;
    if (node >= n) return;
    int lane = threadIdx.x & 63;

    float arv[H];
#pragma unroll
    for (int h4 = 0; h4 < H; h4 += 4) {
        float4 t = *(const float4*)(ar + (size_t)node * H + h4);
        arv[h4] = t.x; arv[h4 + 1] = t.y; arv[h4 + 2] = t.z; arv[h4 + 3] = t.w;
    }
    int beg = rowptr[node], end = rowptr[node + 1];
    float p0[H], p1[H], s[H];
#pragma unroll
    for (int h = 0; h < H; h++) { p0[h] = 0.f; p1[h] = 0.f; s[h] = 0.f; }

    int j0 = beg + lane;
    if (j0 < end) {
        const float* alr = al + (size_t)esrc[j0] * H;
#pragma unroll
        for (int h4 = 0; h4 < H; h4 += 4) {
            float4 t = *(const float4*)(alr + h4);
            float e;
            e = t.x + arv[h4];     e = fmaxf(e, 0.2f * e); p0[h4]     = __expf(fminf(e, 60.f));
            e = t.y + arv[h4 + 1]; e = fmaxf(e, 0.2f * e); p0[h4 + 1] = __expf(fminf(e, 60.f));
            e = t.z + arv[h4 + 2]; e = fmaxf(e, 0.2f * e); p0[h4 + 2] = __expf(fminf(e, 60.f));
            e = t.w + arv[h4 + 3]; e = fmaxf(e, 0.2f * e); p0[h4 + 3] = __expf(fminf(e, 60.f));
        }
#pragma unroll
        for (int h = 0; h < H; h++) s[h] += p0[h];
    }
    int j1 = j0 + 64;
    if (j1 < end) {
        const float* alr = al + (size_t)esrc[j1] * H;
#pragma unroll
        for (int h4 = 0; h4 < H; h4 += 4) {
            float4 t = *(const float4*)(alr + h4);
            float e;
            e = t.x + arv[h4];     e = fmaxf(e, 0.2f * e); p1[h4]     = __expf(fminf(e, 60.f));
            e = t.y + arv[h4 + 1]; e = fmaxf(e, 0.2f * e); p1[h4 + 1] = __expf(fminf(e, 60.f));
            e = t.z + arv[h4 + 2]; e = fmaxf(e, 0.2f * e); p1[h4 + 2] = __expf(fminf(e, 60.f));
            e = t.w + arv[h4 + 3]; e = fmaxf(e, 0.2f * e); p1[h4 + 3] = __expf(fminf(e, 60.f));
        }
#pragma unroll
        for (int h = 0; h < H; h++) s[h] += p1[h];
    }
    for (int j = j0 + 128; j < end; j += 64) {
        const float* alr = al + (size_t)esrc[j] * H;
#pragma unroll
        for (int h = 0; h < H; h++) {
            float e = alr[h] + arv[h];
            e = fmaxf(e, 0.2f * e);
            float p = __expf(fminf(e, 60.f));
            alpha[(size_t)h * Etot + j] = p;
            s[h] += p;
        }
    }
#pragma unroll
    for (int h = 0; h < H; h++) {
        float v = s[h];
#pragma unroll
        for (int off = 32; off > 0; off >>= 1) v += __shfl_xor(v, off, 64);
        s[h] = 1.f / v;
    }
    if (j0 < end) {
#pragma unroll
        for (int h = 0; h < H; h++) alpha[(size_t)h * Etot + j0] = p0[h] * s[h];
    }
    if (j1 < end) {
#pragma unroll
        for (int h = 0; h < H; h++) alpha[(size_t)h * Etot + j1] = p1[h] * s[h];
    }
    for (int j = j0 + 128; j < end; j += 64) {
#pragma unroll
        for (int h = 0; h < H; h++) alpha[(size_t)h * Etot + j] *= s[h];
    }
}

// ---------------------------------------------------------------------------
// agg v7: wave per (node, 128-ch group); lane = (sub 0..3, slot 0..15),
// 16 B/lane gathers. Indices preloaded (deg<=128) + bpermute distribution.
// Main loop: 32-edge batches, 8 independent gathers in flight (4x MLP of v6).
// 8-pack mop-up from preload, direct-load stride-4 tail for the rest.
// ---------------------------------------------------------------------------
template <int HC_, int C>
__global__ __launch_bounds__(256) void gat_agg(
    const bf16_t* __restrict__ hbuf, const float* __restrict__ alpha,
    const int* __restrict__ rowptr, const int* __restrict__ esrc,
    const float* __restrict__ bias, bf16_t* __restrict__ outb,
    int n, int Etot, int nodeblocks) {
    int group = blockIdx.x / nodeblocks;
    int nb    = blockIdx.x - group * nodeblocks;
    int node  = nb * 4 + (threadIdx.x >> 6);
    if (node >= n) return;
    int lane = threadIdx.x & 63;
    int sub  = lane >> 4;          // edge slot 0..3
    int cl   = lane & 15;          // channel slot 0..15
    int gc   = group * 128 + cl * 8;
    int head = gc / C;
    const bf16_t* hb = hbuf + gc;
    const float*  ap = alpha + (size_t)head * Etot;

    float acc[8];
#pragma unroll
    for (int i = 0; i < 8; i++) acc[i] = 0.f;

    int beg = rowptr[node], end = rowptr[node + 1];
    int deg = end - beg;

    // preload first min(deg,128) edge indices, coalesced
    int e0 = 0, e1 = 0;
    {
        int i0 = beg + lane;
        if (i0 < end) e0 = esrc[i0];
        int i1 = beg + 64 + lane;
        if (i1 < end) e1 = esrc[i1];
    }
    int npre = deg < 128 ? deg : 128;
    int nb32 = npre >> 5;          // 32-edge batches

    for (int it = 0; it < nb32; ++it) {
        int kb = it << 5;
        int esel = (kb & 64) ? e1 : e0;      // batches 32-aligned: no straddle
        int sidx[8]; float av[8]; bf16x8 u[8];
#pragma unroll
        for (int q = 0; q < 8; q++) sidx[q] = __shfl(esel, (kb + sub + 4 * q) & 63, 64);
#pragma unroll
        for (int q = 0; q < 8; q++) av[q] = ap[beg + kb + sub + 4 * q];
#pragma unroll
        for (int q = 0; q < 8; q++) u[q] = *(const bf16x8*)(hb + (size_t)sidx[q] * HC_);
#pragma unroll
        for (int q = 0; q < 8; q++) {
            const unsigned int* d = (const unsigned int*)&u[q];
#pragma unroll
            for (int i = 0; i < 4; i++) {
                acc[2 * i]     += av[q] * u2f(d[i] << 16);
                acc[2 * i + 1] += av[q] * u2f(d[i] & 0xffff0000u);
            }
        }
    }
    int done = nb32 << 5;
    int np8 = (npre - done) >> 3;  // 8-edge packs from remaining preload
    for (int p = 0; p < np8; ++p) {
        int kb = done + (p << 3);
        int esel = (kb & 64) ? e1 : e0;
        int s0 = __shfl(esel, (kb + sub) & 63, 64);
        int s1 = __shfl(esel, (kb + sub + 4) & 63, 64);
        float a0 = ap[beg + kb + sub], a1 = ap[beg + kb + sub + 4];
        bf16x8 u0 = *(const bf16x8*)(hb + (size_t)s0 * HC_);
        bf16x8 u1 = *(const bf16x8*)(hb + (size_t)s1 * HC_);
        const unsigned int* d0 = (const unsigned int*)&u0;
        const unsigned int* d1 = (const unsigned int*)&u1;
#pragma unroll
        for (int i = 0; i < 4; i++) {
            acc[2 * i]     += a0 * u2f(d0[i] << 16);
            acc[2 * i + 1] += a0 * u2f(d0[i] & 0xffff0000u);
            acc[2 * i]     += a1 * u2f(d1[i] << 16);
            acc[2 * i + 1] += a1 * u2f(d1[i] & 0xffff0000u);
        }
    }
    done += np8 << 3;
    // tail: pack remainder + deg>128 overflow, stride 4, guarded
    for (int j = beg + done + sub; j < end; j += 4) {
        int s0 = esrc[j];
        float a0 = ap[j];
        bf16x8 u0 = *(const bf16x8*)(hb + (size_t)s0 * HC_);
        const unsigned int* d0 = (const unsigned int*)&u0;
#pragma unroll
        for (int i = 0; i < 4; i++) {
            acc[2 * i]     += a0 * u2f(d0[i] << 16);
            acc[2 * i + 1] += a0 * u2f(d0[i] & 0xffff0000u);
        }
    }
#pragma unroll
    for (int i = 0; i < 8; i++) {
        acc[i] += __shfl_xor(acc[i], 16, 64);
        acc[i] += __shfl_xor(acc[i], 32, 64);
    }
    if (sub == 0) {
        float4 b0 = *(const float4*)(bias + gc);
        float4 b1 = *(const float4*)(bias + gc + 4);
        float bb[8] = {b0.x, b0.y, b0.z, b0.w, b1.x, b1.y, b1.z, b1.w};
        bf16x8 outv;
        unsigned short* ov = (unsigned short*)&outv;
#pragma unroll
        for (int i = 0; i < 8; i++) ov[i] = f2bf(fmaxf(acc[i] + bb[i], 0.f));
        *(bf16x8*)(outb + (size_t)node * HC_ + gc) = outv;
    }
}

// ---------------------------------------------------------------------------
// Fused head: out1 = sigmoid(concat(x1,x2,x3).Wf + bf); then MLP -> out2.
// ---------------------------------------------------------------------------
__global__ __launch_bounds__(256) void head_fused(
    const float* __restrict__ x, const bf16_t* __restrict__ x1b,
    const bf16_t* __restrict__ x2b, const bf16_t* __restrict__ x3b,
    const float* __restrict__ Wf, const float* __restrict__ bfc,
    const float* __restrict__ M1w, const float* __restrict__ M1b,
    const float* __restrict__ M2w, const float* __restrict__ M2b,
    const float* __restrict__ M3w, const float* __restrict__ M3b,
    float* __restrict__ out1, float* __restrict__ out2, int n) {
    __shared__ float h1s[4][128];
    int w    = threadIdx.x >> 6;
    int lane = threadIdx.x & 63;
    int node = blockIdx.x * 4 + w;
    bool valid = node < n;
    int nd = valid ? node : 0;

    float s = 0.f;
    {
        ushort4 u = *(const ushort4*)(x1b + (size_t)nd * 256 + lane * 4);
        const float* wv = Wf + lane * 4;
        s += bf2f(u.x) * wv[0] + bf2f(u.y) * wv[1] + bf2f(u.z) * wv[2] + bf2f(u.w) * wv[3];
    }
    {
        ushort4 u = *(const ushort4*)(x2b + (size_t)nd * 256 + lane * 4);
        const float* wv = Wf + 256 + lane * 4;
        s += bf2f(u.x) * wv[0] + bf2f(u.y) * wv[1] + bf2f(u.z) * wv[2] + bf2f(u.w) * wv[3];
    }
#pragma unroll
    for (int i = 0; i < 3; i++) {
        int k = i * 256 + lane * 4;
        ushort4 u = *(const ushort4*)(x3b + (size_t)nd * 768 + k);
        const float* wv = Wf + 512 + k;
        s += bf2f(u.x) * wv[0] + bf2f(u.y) * wv[1] + bf2f(u.z) * wv[2] + bf2f(u.w) * wv[3];
    }
#pragma unroll
    for (int off = 32; off > 0; off >>= 1) s += __shfl_xor(s, off, 64);
    float so = 1.f / (1.f + __expf(-(s + bfc[0])));
    if (lane == 0 && valid) out1[node] = so;

    float xm[17];
#pragma unroll
    for (int k = 0; k < 16; k++) xm[k] = x[nd * 16 + k];
    xm[16] = so;

    float a0 = M1b[lane], a1 = M1b[lane + 64];
#pragma unroll
    for (int k = 0; k < 17; k++) {
        a0 += xm[k] * M1w[k * 128 + lane];
        a1 += xm[k] * M1w[k * 128 + lane + 64];
    }
    h1s[w][lane]      = fmaxf(a0, 0.f);
    h1s[w][lane + 64] = fmaxf(a1, 0.f);
    __syncthreads();

    float b0 = M2b[lane];
#pragma unroll 16
    for (int k = 0; k < 128; k++) b0 += h1s[w][k] * M2w[k * 64 + lane];
    b0 = fmaxf(b0, 0.f);

    float p = b0 * M3w[lane];
#pragma unroll
    for (int off = 32; off > 0; off >>= 1) p += __shfl_xor(p, off, 64);
    if (lane == 0 && valid) out2[node] = 1.f / (1.f + __expf(-(p + M3b[0])));
}

// ---------------------------------------------------------------------------
extern "C" void kernel_launch(void* const* d_in, const int* in_sizes, int n_in,
                              void* d_out, int out_size, void* d_ws, size_t ws_size,
                              hipStream_t stream) {
    const float* x   = (const float*)d_in[0];
    const int*   ei  = (const int*)d_in[1];
    const float* W1  = (const float*)d_in[3];
    const float* a1s = (const float*)d_in[4];
    const float* a1d = (const float*)d_in[5];
    const float* b1  = (const float*)d_in[6];
    const float* W2  = (const float*)d_in[7];
    const float* a2s = (const float*)d_in[8];
    const float* a2d = (const float*)d_in[9];
    const float* b2  = (const float*)d_in[10];
    const float* W3  = (const float*)d_in[11];
    const float* a3s = (const float*)d_in[12];
    const float* a3d = (const float*)d_in[13];
    const float* b3  = (const float*)d_in[14];
    const float* Wf  = (const float*)d_in[15];
    const float* bf  = (const float*)d_in[16];
    const float* M1w = (const float*)d_in[17];
    const float* M1b = (const float*)d_in[18];
    const float* M2w = (const float*)d_in[19];
    const float* M2b = (const float*)d_in[20];
    const float* M3w = (const float*)d_in[21];
    const float* M3b = (const float*)d_in[22];

    const int N = in_sizes[0] / 16;        // 10000
    const int E = in_sizes[1] / 2;         // 320000
    const int Etot = E + N;

    char* base = (char*)d_ws;
    size_t off = 0;
    auto carve = [&](size_t bytes) {
        char* p = base + off;
        off = (off + bytes + 255) & ~(size_t)255;
        return p;
    };
    bf16_t* hbuf   = (bf16_t*)carve((size_t)N * 768 * 2);
    bf16_t* x1b    = (bf16_t*)carve((size_t)N * 256 * 2);
    bf16_t* x2b    = (bf16_t*)carve((size_t)N * 256 * 2);
    bf16_t* x3b    = (bf16_t*)carve((size_t)N * 768 * 2);
    bf16_t* Wt2    = (bf16_t*)carve((size_t)256 * 256 * 2);
    bf16_t* Wt3    = (bf16_t*)carve((size_t)256 * 768 * 2);
    float*  al     = (float*)carve((size_t)N * 12 * 4);
    float*  ar     = (float*)carve((size_t)N * 12 * 4);
    float*  alphab = (float*)carve((size_t)Etot * 12 * 4);
    int*    rowptr = (int*)carve((size_t)(N + 1) * 4);
    int*    cnt2   = (int*)carve((size_t)(2 * N) * 4);   // counts | cursor contiguous
    int*    counts = cnt2;
    int*    cursor = cnt2 + N;
    int*    esrc   = (int*)carve((size_t)Etot * 4);
    (void)ws_size;

    float* out1 = (float*)d_out;
    float* out2 = (float*)d_out + N;

    const int TB = 256;
    int eb = (Etot + TB - 1) / TB;
    int nodeblocks = (N + 3) / 4;          // 4 node-waves per block

    // --- CSR by dst + weight prep ---
    zero_i32<<<(2 * N + TB - 1) / TB, TB, 0, stream>>>(cnt2, 2 * N);
    count_edges<<<eb, TB, 0, stream>>>(ei, E, N, counts);
    scan_rowptr<<<1, 1024, 0, stream>>>(counts, rowptr, N);
    fill_edges<<<eb, TB, 0, stream>>>(ei, E, N, rowptr, cursor, esrc);
    transpose_cast2<<<dim3(16, 64), TB, 0, stream>>>(W2, Wt2, W3, Wt3);

    // --- layer 1: 16 -> 8x32 (fp32 gemm + fused scores) ---
    gemm_f32_sc<<<dim3(4, (N + 63) / 64), TB, 0, stream>>>(x, W1, hbuf, a1s, a1d, al, ar, N, 16, 256, 8);
    alpha_node<8><<<nodeblocks, TB, 0, stream>>>(al, ar, rowptr, esrc, alphab, N, Etot);
    gat_agg<256, 32><<<2 * nodeblocks, TB, 0, stream>>>(hbuf, alphab, rowptr, esrc, b1, x1b, N, Etot, nodeblocks);

    // --- layer 2: 256 -> 8x32 (MFMA + fused scores) ---
    gemm_mfma_sc<32><<<dim3(4, (N + 127) / 128), TB, 0, stream>>>(x1b, Wt2, hbuf, a2s, a2d, al, ar, N, 256, 256, 8);
    alpha_node<8><<<nodeblocks, TB, 0, stream>>>(al, ar, rowptr, esrc, alphab, N, Etot);
    gat_agg<256, 32><<<2 * nodeblocks, TB, 0, stream>>>(hbuf, alphab, rowptr, esrc, b2, x2b, N, Etot, nodeblocks);

    // --- layer 3: 256 -> 12x64 (MFMA + fused scores) ---
    gemm_mfma_sc<64><<<dim3(12, (N + 127) / 128), TB, 0, stream>>>(x2b, Wt3, hbuf, a3s, a3d, al, ar, N, 256, 768, 12);
    alpha_node<12><<<nodeblocks, TB, 0, stream>>>(al, ar, rowptr, esrc, alphab, N, Etot);
    gat_agg<768, 64><<<6 * nodeblocks, TB, 0, stream>>>(hbuf, alphab, rowptr, esrc, b3, x3b, N, Etot, nodeblocks);

    // --- fused final linear + MLP ---
    head_fused<<<nodeblocks, TB, 0, stream>>>(x, x1b, x2b, x3b, Wf, bf,
                                              M1w, M1b, M2w, M2b, M3w, M3b, out1, out2, N);
}

// Round 11
// 335.099 us; speedup vs baseline: 1.0770x; 1.0770x over previous
//
#include <hip/hip_runtime.h>
#include <math.h>

// ---------------------------------------------------------------------------
// GATNet (3x GATConv + final linear + MLP), MI355X.
// R10: keep R9's fused-score GEMMs (-3 dispatches, ~20us win); revert agg to
// R8 v6 (depth-2 pipelined 8-edge packs, preloaded indices, VGPR32/occ68%) —
// R9's 32-edge batches regressed (occ 35%, half of edges unpipelined).
// ---------------------------------------------------------------------------

typedef unsigned short bf16_t;
typedef __attribute__((ext_vector_type(8))) short bf16x8;
typedef __attribute__((ext_vector_type(4))) float f32x4;

__device__ inline float bf2f(bf16_t u) {
    union { unsigned int i; float f; } v; v.i = ((unsigned int)u) << 16; return v.f;
}
__device__ inline float u2f(unsigned int x) {
    union { unsigned int i; float f; } v; v.i = x; return v.f;
}
__device__ inline bf16_t f2bf(float f) {
    union { float f; unsigned int i; } v; v.f = f;
    unsigned int r = v.i + 0x7FFF + ((v.i >> 16) & 1);   // round-nearest-even
    return (bf16_t)(r >> 16);
}

// ------------------------------ CSR build ----------------------------------

__global__ void zero_i32(int* p, int n) {
    int i = blockIdx.x * blockDim.x + threadIdx.x;
    if (i < n) p[i] = 0;
}

__global__ void count_edges(const int* __restrict__ ei, int E, int Nn,
                            int* __restrict__ counts) {
    int e = blockIdx.x * blockDim.x + threadIdx.x;
    if (e >= E + Nn) return;
    int dst = (e < E) ? ei[E + e] : (e - E);   // self-loops appended
    atomicAdd(&counts[dst], 1);
}

// single block, 1024 threads: serial-per-thread + shuffle block scan
__global__ __launch_bounds__(1024) void scan_rowptr(const int* __restrict__ counts,
                                                    int* __restrict__ rowptr, int n) {
    const int IPT = (n + 1023) / 1024;   // <=16
    int t = threadIdx.x;
    int base = t * IPT;
    int loc[16];
    int run = 0;
#pragma unroll
    for (int i = 0; i < 16; i++) {
        if (i >= IPT) break;
        int idx = base + i;
        int v = (idx < n) ? counts[idx] : 0;
        loc[i] = run;
        run += v;
    }
    int lane = t & 63, wid = t >> 6;
    int v = run;
    for (int off = 1; off < 64; off <<= 1) {
        int u = __shfl_up(v, off, 64);
        if (lane >= off) v += u;
    }
    __shared__ int wsum[16];
    __shared__ int woff[16];
    if (lane == 63) wsum[wid] = v;
    __syncthreads();
    if (t == 0) { int s = 0; for (int i = 0; i < 16; i++) { woff[i] = s; s += wsum[i]; } }
    __syncthreads();
    int excl = v - run + woff[wid];
#pragma unroll
    for (int i = 0; i < 16; i++) {
        if (i >= IPT) break;
        int idx = base + i;
        if (idx < n) rowptr[idx] = excl + loc[i];
    }
    if (t == 1023) rowptr[n] = excl + run;
}

__global__ void fill_edges(const int* __restrict__ ei, int E, int Nn,
                           const int* __restrict__ rowptr, int* __restrict__ cursor,
                           int* __restrict__ edge_src) {
    int e = blockIdx.x * blockDim.x + threadIdx.x;
    if (e >= E + Nn) return;
    int src, dst;
    if (e < E) { src = ei[e]; dst = ei[E + e]; }
    else       { src = e - E; dst = src; }
    int pos = atomicAdd(&cursor[dst], 1);
    edge_src[rowptr[dst] + pos] = src;
}

// ---------------------------------------------------------------------------
// Fused transpose+cast for both weight matrices (K=256 each).
// ---------------------------------------------------------------------------
__global__ __launch_bounds__(256) void transpose_cast2(const float* __restrict__ W2,
                                                       bf16_t* __restrict__ Wt2,
                                                       const float* __restrict__ W3,
                                                       bf16_t* __restrict__ Wt3) {
    __shared__ float tile[16][17];
    const float* W; bf16_t* Wt; int Nc, n0;
    if (blockIdx.y < 16) { W = W2; Wt = Wt2; Nc = 256; n0 = blockIdx.y * 16; }
    else                 { W = W3; Wt = Wt3; Nc = 768; n0 = (blockIdx.y - 16) * 16; }
    int k0 = blockIdx.x * 16;
    int tx = threadIdx.x & 15, ty = threadIdx.x >> 4;
    tile[ty][tx] = W[(size_t)(k0 + ty) * Nc + n0 + tx];
    __syncthreads();
    Wt[(size_t)(n0 + ty) * 256 + k0 + tx] = f2bf(tile[tx][ty]);
}

// ---------------------------------------------------------------------------
// fp32 GEMM (layer 1, K=16, C=32, H=8), bf16 out + fused al/ar scores.
// ---------------------------------------------------------------------------
__global__ __launch_bounds__(256) void gemm_f32_sc(const float* __restrict__ A,
                                                   const float* __restrict__ B,
                                                   bf16_t* __restrict__ Cm,
                                                   const float* __restrict__ a_s,
                                                   const float* __restrict__ a_d,
                                                   float* __restrict__ al,
                                                   float* __restrict__ ar,
                                                   int M, int K, int Nc, int H) {
    __shared__ float As[16][64];
    __shared__ float Bs[16][64];
    int t  = threadIdx.x;
    int tx = t & 15, ty = t >> 4;
    int row0 = blockIdx.y * 64, col0 = blockIdx.x * 64;
    int a_r = t >> 2, a_c = (t & 3) * 4;
    int b_r = t >> 4, b_c = (t & 15) * 4;

    float acc[4][4];
#pragma unroll
    for (int i = 0; i < 4; i++)
#pragma unroll
        for (int j = 0; j < 4; j++) acc[i][j] = 0.f;

    for (int kt = 0; kt < K; kt += 16) {
        float4 av = make_float4(0.f, 0.f, 0.f, 0.f);
        int gr = row0 + a_r;
        if (gr < M) av = *(const float4*)(A + (size_t)gr * K + kt + a_c);
        As[a_c + 0][a_r] = av.x;
        As[a_c + 1][a_r] = av.y;
        As[a_c + 2][a_r] = av.z;
        As[a_c + 3][a_r] = av.w;
        float4 bv = *(const float4*)(B + (size_t)(kt + b_r) * Nc + col0 + b_c);
        *(float4*)&Bs[b_r][b_c] = bv;
        __syncthreads();
#pragma unroll
        for (int k = 0; k < 16; k++) {
            float4 a4 = *(const float4*)&As[k][ty * 4];
            float4 b4 = *(const float4*)&Bs[k][tx * 4];
            float aa[4] = {a4.x, a4.y, a4.z, a4.w};
            float bb[4] = {b4.x, b4.y, b4.z, b4.w};
#pragma unroll
            for (int i = 0; i < 4; i++)
#pragma unroll
                for (int j = 0; j < 4; j++) acc[i][j] += aa[i] * bb[j];
        }
        __syncthreads();
    }
    float4 asv = *(const float4*)(a_s + col0 + tx * 4);
    float4 adv = *(const float4*)(a_d + col0 + tx * 4);
#pragma unroll
    for (int i = 0; i < 4; i++) {
        int gr = row0 + ty * 4 + i;
        float sa = acc[i][0] * asv.x + acc[i][1] * asv.y + acc[i][2] * asv.z + acc[i][3] * asv.w;
        float sd = acc[i][0] * adv.x + acc[i][1] * adv.y + acc[i][2] * adv.z + acc[i][3] * adv.w;
#pragma unroll
        for (int off = 4; off > 0; off >>= 1) {
            sa += __shfl_xor(sa, off, 64);
            sd += __shfl_xor(sd, off, 64);
        }
        if ((tx == 0 || tx == 8) && gr < M) {
            int h = (col0 >> 5) + (tx >> 3);
            al[gr * H + h] = sa;
            ar[gr * H + h] = sd;
        }
        if (gr < M) {
            ushort4 v;
            v.x = f2bf(acc[i][0]); v.y = f2bf(acc[i][1]);
            v.z = f2bf(acc[i][2]); v.w = f2bf(acc[i][3]);
            *(ushort4*)(Cm + (size_t)gr * Nc + col0 + tx * 4) = v;
        }
    }
}

// ---------------------------------------------------------------------------
// MFMA bf16 GEMM (layers 2/3) + fused al/ar scores (block-local, no atomics).
// ---------------------------------------------------------------------------
template <int C_>
__global__ __launch_bounds__(256) void gemm_mfma_sc(const bf16_t* __restrict__ A,
                                                    const bf16_t* __restrict__ Bt,
                                                    bf16_t* __restrict__ Cm,
                                                    const float* __restrict__ a_s,
                                                    const float* __restrict__ a_d,
                                                    float* __restrict__ al,
                                                    float* __restrict__ ar,
                                                    int M, int K, int Nc, int H) {
    int wave = threadIdx.x >> 6, lane = threadIdx.x & 63;
    int quad = lane >> 4, l16 = lane & 15;
    int m0 = blockIdx.y * 128 + wave * 32;
    int n0 = blockIdx.x * 64;

    f32x4 acc[2][4];
    f32x4 z = {0.f, 0.f, 0.f, 0.f};
#pragma unroll
    for (int i = 0; i < 2; i++)
#pragma unroll
        for (int j = 0; j < 4; j++) acc[i][j] = z;

    int r0 = m0 + l16;       if (r0 >= M) r0 = M - 1;
    int r1 = m0 + 16 + l16;  if (r1 >= M) r1 = M - 1;
    const bf16_t* Ap0 = A + (size_t)r0 * K + quad * 8;
    const bf16_t* Ap1 = A + (size_t)r1 * K + quad * 8;
    const bf16_t* Bp0 = Bt + (size_t)(n0 + 0  + l16) * K + quad * 8;
    const bf16_t* Bp1 = Bt + (size_t)(n0 + 16 + l16) * K + quad * 8;
    const bf16_t* Bp2 = Bt + (size_t)(n0 + 32 + l16) * K + quad * 8;
    const bf16_t* Bp3 = Bt + (size_t)(n0 + 48 + l16) * K + quad * 8;

    for (int kt = 0; kt < K; kt += 32) {
        bf16x8 a0 = *(const bf16x8*)(Ap0 + kt);
        bf16x8 a1 = *(const bf16x8*)(Ap1 + kt);
        bf16x8 b0 = *(const bf16x8*)(Bp0 + kt);
        bf16x8 b1 = *(const bf16x8*)(Bp1 + kt);
        bf16x8 b2 = *(const bf16x8*)(Bp2 + kt);
        bf16x8 b3 = *(const bf16x8*)(Bp3 + kt);
        acc[0][0] = __builtin_amdgcn_mfma_f32_16x16x32_bf16(a0, b0, acc[0][0], 0, 0, 0);
        acc[1][0] = __builtin_amdgcn_mfma_f32_16x16x32_bf16(a1, b0, acc[1][0], 0, 0, 0);
        acc[0][1] = __builtin_amdgcn_mfma_f32_16x16x32_bf16(a0, b1, acc[0][1], 0, 0, 0);
        acc[1][1] = __builtin_amdgcn_mfma_f32_16x16x32_bf16(a1, b1, acc[1][1], 0, 0, 0);
        acc[0][2] = __builtin_amdgcn_mfma_f32_16x16x32_bf16(a0, b2, acc[0][2], 0, 0, 0);
        acc[1][2] = __builtin_amdgcn_mfma_f32_16x16x32_bf16(a1, b2, acc[1][2], 0, 0, 0);
        acc[0][3] = __builtin_amdgcn_mfma_f32_16x16x32_bf16(a0, b3, acc[0][3], 0, 0, 0);
        acc[1][3] = __builtin_amdgcn_mfma_f32_16x16x32_bf16(a1, b3, acc[1][3], 0, 0, 0);
    }

    float asv[4], adv[4];
#pragma unroll
    for (int j = 0; j < 4; j++) {
        asv[j] = a_s[n0 + j * 16 + l16];
        adv[j] = a_d[n0 + j * 16 + l16];
    }
#pragma unroll
    for (int i = 0; i < 2; i++)
#pragma unroll
        for (int r = 0; r < 4; r++) {
            int gr = m0 + i * 16 + quad * 4 + r;
            if (C_ == 64) {
                float sa = acc[i][0][r] * asv[0] + acc[i][1][r] * asv[1]
                         + acc[i][2][r] * asv[2] + acc[i][3][r] * asv[3];
                float sd = acc[i][0][r] * adv[0] + acc[i][1][r] * adv[1]
                         + acc[i][2][r] * adv[2] + acc[i][3][r] * adv[3];
#pragma unroll
                for (int off = 8; off > 0; off >>= 1) {
                    sa += __shfl_xor(sa, off, 64);
                    sd += __shfl_xor(sd, off, 64);
                }
                if (l16 == 0 && gr < M) {
                    int h = n0 >> 6;
                    al[gr * H + h] = sa;
                    ar[gr * H + h] = sd;
                }
            } else {
                float saA = acc[i][0][r] * asv[0] + acc[i][1][r] * asv[1];
                float saB = acc[i][2][r] * asv[2] + acc[i][3][r] * asv[3];
                float sdA = acc[i][0][r] * adv[0] + acc[i][1][r] * adv[1];
                float sdB = acc[i][2][r] * adv[2] + acc[i][3][r] * adv[3];
#pragma unroll
                for (int off = 8; off > 0; off >>= 1) {
                    saA += __shfl_xor(saA, off, 64);
                    saB += __shfl_xor(saB, off, 64);
                    sdA += __shfl_xor(sdA, off, 64);
                    sdB += __shfl_xor(sdB, off, 64);
                }
                if (l16 == 0 && gr < M) {
                    int h = n0 >> 5;
                    al[gr * H + h]     = saA;
                    ar[gr * H + h]     = sdA;
                    al[gr * H + h + 1] = saB;
                    ar[gr * H + h + 1] = sdB;
                }
            }
        }
#pragma unroll
    for (int i = 0; i < 2; i++)
#pragma unroll
        for (int j = 0; j < 4; j++)
#pragma unroll
            for (int r = 0; r < 4; r++) {
                int gr = m0 + i * 16 + quad * 4 + r;
                if (gr < M) Cm[(size_t)gr * Nc + n0 + j * 16 + l16] = f2bf(acc[i][j][r]);
            }
}

// ---------------------------------------------------------------------------
// alpha v2: wave per node, ALL heads; row-contiguous al reads; register p
// for deg<=128, guarded tail beyond; per-head shuffle reduce; planar stores.
// ---------------------------------------------------------------------------
template <int H>
__global__ __launch_bounds__(256) void alpha_node(const float* __restrict__ al,
                                                  const float* __restrict__ ar,
                                                  const int* __restrict__ rowptr,
                                                  const int* __restrict__ esrc,
                                                  float* __restrict__ alpha,
                                                  int n, int Etot) {
    int node = (blockIdx.x * blockDim.x + threadIdx.x) >> 6;
    if (node >= n) return;
    int lane = threadIdx.x & 63;

    float arv[H];
#pragma unroll
    for (int h4 = 0; h4 < H; h4 += 4) {
        float4 t = *(const float4*)(ar + (size_t)node * H + h4);
        arv[h4] = t.x; arv[h4 + 1] = t.y; arv[h4 + 2] = t.z; arv[h4 + 3] = t.w;
    }
    int beg = rowptr[node], end = rowptr[node + 1];
    float p0[H], p1[H], s[H];
#pragma unroll
    for (int h = 0; h < H; h++) { p0[h] = 0.f; p1[h] = 0.f; s[h] = 0.f; }

    int j0 = beg + lane;
    if (j0 < end) {
        const float* alr = al + (size_t)esrc[j0] * H;
#pragma unroll
        for (int h4 = 0; h4 < H; h4 += 4) {
            float4 t = *(const float4*)(alr + h4);
            float e;
            e = t.x + arv[h4];     e = fmaxf(e, 0.2f * e); p0[h4]     = __expf(fminf(e, 60.f));
            e = t.y + arv[h4 + 1]; e = fmaxf(e, 0.2f * e); p0[h4 + 1] = __expf(fminf(e, 60.f));
            e = t.z + arv[h4 + 2]; e = fmaxf(e, 0.2f * e); p0[h4 + 2] = __expf(fminf(e, 60.f));
            e = t.w + arv[h4 + 3]; e = fmaxf(e, 0.2f * e); p0[h4 + 3] = __expf(fminf(e, 60.f));
        }
#pragma unroll
        for (int h = 0; h < H; h++) s[h] += p0[h];
    }
    int j1 = j0 + 64;
    if (j1 < end) {
        const float* alr = al + (size_t)esrc[j1] * H;
#pragma unroll
        for (int h4 = 0; h4 < H; h4 += 4) {
            float4 t = *(const float4*)(alr + h4);
            float e;
            e = t.x + arv[h4];     e = fmaxf(e, 0.2f * e); p1[h4]     = __expf(fminf(e, 60.f));
            e = t.y + arv[h4 + 1]; e = fmaxf(e, 0.2f * e); p1[h4 + 1] = __expf(fminf(e, 60.f));
            e = t.z + arv[h4 + 2]; e = fmaxf(e, 0.2f * e); p1[h4 + 2] = __expf(fminf(e, 60.f));
            e = t.w + arv[h4 + 3]; e = fmaxf(e, 0.2f * e); p1[h4 + 3] = __expf(fminf(e, 60.f));
        }
#pragma unroll
        for (int h = 0; h < H; h++) s[h] += p1[h];
    }
    for (int j = j0 + 128; j < end; j += 64) {
        const float* alr = al + (size_t)esrc[j] * H;
#pragma unroll
        for (int h = 0; h < H; h++) {
            float e = alr[h] + arv[h];
            e = fmaxf(e, 0.2f * e);
            float p = __expf(fminf(e, 60.f));
            alpha[(size_t)h * Etot + j] = p;
            s[h] += p;
        }
    }
#pragma unroll
    for (int h = 0; h < H; h++) {
        float v = s[h];
#pragma unroll
        for (int off = 32; off > 0; off >>= 1) v += __shfl_xor(v, off, 64);
        s[h] = 1.f / v;
    }
    if (j0 < end) {
#pragma unroll
        for (int h = 0; h < H; h++) alpha[(size_t)h * Etot + j0] = p0[h] * s[h];
    }
    if (j1 < end) {
#pragma unroll
        for (int h = 0; h < H; h++) alpha[(size_t)h * Etot + j1] = p1[h] * s[h];
    }
    for (int j = j0 + 128; j < end; j += 64) {
#pragma unroll
        for (int h = 0; h < H; h++) alpha[(size_t)h * Etot + j] *= s[h];
    }
}

// ---------------------------------------------------------------------------
// agg v6 (R8): wave per (node, 128-ch group); lane = (sub 0..3, slot 0..15),
// 16 B/lane gathers. Indices preloaded (deg<=128) + bpermute distribution;
// depth-2 pipelined 8-edge packs; direct-load stride-4 tail.
// ---------------------------------------------------------------------------
template <int HC_, int C>
__global__ __launch_bounds__(256) void gat_agg(
    const bf16_t* __restrict__ hbuf, const float* __restrict__ alpha,
    const int* __restrict__ rowptr, const int* __restrict__ esrc,
    const float* __restrict__ bias, bf16_t* __restrict__ outb,
    int n, int Etot, int nodeblocks) {
    int group = blockIdx.x / nodeblocks;
    int nb    = blockIdx.x - group * nodeblocks;
    int node  = nb * 4 + (threadIdx.x >> 6);
    if (node >= n) return;
    int lane = threadIdx.x & 63;
    int sub  = lane >> 4;          // edge slot 0..3
    int cl   = lane & 15;          // channel slot 0..15
    int gc   = group * 128 + cl * 8;
    int head = gc / C;
    const bf16_t* hb = hbuf + gc;
    const float*  ap = alpha + (size_t)head * Etot;

    float acc[8];
#pragma unroll
    for (int i = 0; i < 8; i++) acc[i] = 0.f;

    int beg = rowptr[node], end = rowptr[node + 1];
    int deg = end - beg;

    // preload first min(deg,128) edge indices, coalesced
    int e0 = 0, e1 = 0;
    {
        int i0 = beg + lane;
        if (i0 < end) e0 = esrc[i0];
        int i1 = beg + 64 + lane;
        if (i1 < end) e1 = esrc[i1];
    }
    int npre  = deg < 128 ? deg : 128;
    int nfull = npre >> 3;         // 8-edge packs from preloaded region

    if (nfull > 0) {
        int s0 = __shfl(e0, sub, 64);
        int s1 = __shfl(e0, sub + 4, 64);
        float a0 = ap[beg + sub], a1 = ap[beg + sub + 4];
        bf16x8 u0 = *(const bf16x8*)(hb + (size_t)s0 * HC_);
        bf16x8 u1 = *(const bf16x8*)(hb + (size_t)s1 * HC_);
        for (int it = 1; it < nfull; ++it) {
            int kb = it * 8;
            int esel = (kb < 64) ? e0 : e1;      // loop-uniform select
            int t0 = __shfl(esel, (kb + sub) & 63, 64);
            int t1 = __shfl(esel, (kb + sub + 4) & 63, 64);
            float b0v = ap[beg + kb + sub], b1v = ap[beg + kb + sub + 4];
            bf16x8 v0 = *(const bf16x8*)(hb + (size_t)t0 * HC_);
            bf16x8 v1 = *(const bf16x8*)(hb + (size_t)t1 * HC_);
            const unsigned int* d0 = (const unsigned int*)&u0;
            const unsigned int* d1 = (const unsigned int*)&u1;
#pragma unroll
            for (int i = 0; i < 4; i++) {
                acc[2 * i]     += a0 * u2f(d0[i] << 16);
                acc[2 * i + 1] += a0 * u2f(d0[i] & 0xffff0000u);
                acc[2 * i]     += a1 * u2f(d1[i] << 16);
                acc[2 * i + 1] += a1 * u2f(d1[i] & 0xffff0000u);
            }
            u0 = v0; u1 = v1; a0 = b0v; a1 = b1v;
        }
        const unsigned int* d0 = (const unsigned int*)&u0;
        const unsigned int* d1 = (const unsigned int*)&u1;
#pragma unroll
        for (int i = 0; i < 4; i++) {
            acc[2 * i]     += a0 * u2f(d0[i] << 16);
            acc[2 * i + 1] += a0 * u2f(d0[i] & 0xffff0000u);
            acc[2 * i]     += a1 * u2f(d1[i] << 16);
            acc[2 * i + 1] += a1 * u2f(d1[i] & 0xffff0000u);
        }
    }
    // tail: pack remainder + deg>128 overflow, stride 4, guarded
    for (int j = beg + (nfull << 3) + sub; j < end; j += 4) {
        int s0 = esrc[j];
        float a0 = ap[j];
        bf16x8 u0 = *(const bf16x8*)(hb + (size_t)s0 * HC_);
        const unsigned int* d0 = (const unsigned int*)&u0;
#pragma unroll
        for (int i = 0; i < 4; i++) {
            acc[2 * i]     += a0 * u2f(d0[i] << 16);
            acc[2 * i + 1] += a0 * u2f(d0[i] & 0xffff0000u);
        }
    }
#pragma unroll
    for (int i = 0; i < 8; i++) {
        acc[i] += __shfl_xor(acc[i], 16, 64);
        acc[i] += __shfl_xor(acc[i], 32, 64);
    }
    if (sub == 0) {
        float4 b0 = *(const float4*)(bias + gc);
        float4 b1 = *(const float4*)(bias + gc + 4);
        float bb[8] = {b0.x, b0.y, b0.z, b0.w, b1.x, b1.y, b1.z, b1.w};
        bf16x8 outv;
        unsigned short* ov = (unsigned short*)&outv;
#pragma unroll
        for (int i = 0; i < 8; i++) ov[i] = f2bf(fmaxf(acc[i] + bb[i], 0.f));
        *(bf16x8*)(outb + (size_t)node * HC_ + gc) = outv;
    }
}

// ---------------------------------------------------------------------------
// Fused head: out1 = sigmoid(concat(x1,x2,x3).Wf + bf); then MLP -> out2.
// ---------------------------------------------------------------------------
__global__ __launch_bounds__(256) void head_fused(
    const float* __restrict__ x, const bf16_t* __restrict__ x1b,
    const bf16_t* __restrict__ x2b, const bf16_t* __restrict__ x3b,
    const float* __restrict__ Wf, const float* __restrict__ bfc,
    const float* __restrict__ M1w, const float* __restrict__ M1b,
    const float* __restrict__ M2w, const float* __restrict__ M2b,
    const float* __restrict__ M3w, const float* __restrict__ M3b,
    float* __restrict__ out1, float* __restrict__ out2, int n) {
    __shared__ float h1s[4][128];
    int w    = threadIdx.x >> 6;
    int lane = threadIdx.x & 63;
    int node = blockIdx.x * 4 + w;
    bool valid = node < n;
    int nd = valid ? node : 0;

    float s = 0.f;
    {
        ushort4 u = *(const ushort4*)(x1b + (size_t)nd * 256 + lane * 4);
        const float* wv = Wf + lane * 4;
        s += bf2f(u.x) * wv[0] + bf2f(u.y) * wv[1] + bf2f(u.z) * wv[2] + bf2f(u.w) * wv[3];
    }
    {
        ushort4 u = *(const ushort4*)(x2b + (size_t)nd * 256 + lane * 4);
        const float* wv = Wf + 256 + lane * 4;
        s += bf2f(u.x) * wv[0] + bf2f(u.y) * wv[1] + bf2f(u.z) * wv[2] + bf2f(u.w) * wv[3];
    }
#pragma unroll
    for (int i = 0; i < 3; i++) {
        int k = i * 256 + lane * 4;
        ushort4 u = *(const ushort4*)(x3b + (size_t)nd * 768 + k);
        const float* wv = Wf + 512 + k;
        s += bf2f(u.x) * wv[0] + bf2f(u.y) * wv[1] + bf2f(u.z) * wv[2] + bf2f(u.w) * wv[3];
    }
#pragma unroll
    for (int off = 32; off > 0; off >>= 1) s += __shfl_xor(s, off, 64);
    float so = 1.f / (1.f + __expf(-(s + bfc[0])));
    if (lane == 0 && valid) out1[node] = so;

    float xm[17];
#pragma unroll
    for (int k = 0; k < 16; k++) xm[k] = x[nd * 16 + k];
    xm[16] = so;

    float a0 = M1b[lane], a1 = M1b[lane + 64];
#pragma unroll
    for (int k = 0; k < 17; k++) {
        a0 += xm[k] * M1w[k * 128 + lane];
        a1 += xm[k] * M1w[k * 128 + lane + 64];
    }
    h1s[w][lane]      = fmaxf(a0, 0.f);
    h1s[w][lane + 64] = fmaxf(a1, 0.f);
    __syncthreads();

    float b0 = M2b[lane];
#pragma unroll 16
    for (int k = 0; k < 128; k++) b0 += h1s[w][k] * M2w[k * 64 + lane];
    b0 = fmaxf(b0, 0.f);

    float p = b0 * M3w[lane];
#pragma unroll
    for (int off = 32; off > 0; off >>= 1) p += __shfl_xor(p, off, 64);
    if (lane == 0 && valid) out2[node] = 1.f / (1.f + __expf(-(p + M3b[0])));
}

// ---------------------------------------------------------------------------
extern "C" void kernel_launch(void* const* d_in, const int* in_sizes, int n_in,
                              void* d_out, int out_size, void* d_ws, size_t ws_size,
                              hipStream_t stream) {
    const float* x   = (const float*)d_in[0];
    const int*   ei  = (const int*)d_in[1];
    const float* W1  = (const float*)d_in[3];
    const float* a1s = (const float*)d_in[4];
    const float* a1d = (const float*)d_in[5];
    const float* b1  = (const float*)d_in[6];
    const float* W2  = (const float*)d_in[7];
    const float* a2s = (const float*)d_in[8];
    const float* a2d = (const float*)d_in[9];
    const float* b2  = (const float*)d_in[10];
    const float* W3  = (const float*)d_in[11];
    const float* a3s = (const float*)d_in[12];
    const float* a3d = (const float*)d_in[13];
    const float* b3  = (const float*)d_in[14];
    const float* Wf  = (const float*)d_in[15];
    const float* bf  = (const float*)d_in[16];
    const float* M1w = (const float*)d_in[17];
    const float* M1b = (const float*)d_in[18];
    const float* M2w = (const float*)d_in[19];
    const float* M2b = (const float*)d_in[20];
    const float* M3w = (const float*)d_in[21];
    const float* M3b = (const float*)d_in[22];

    const int N = in_sizes[0] / 16;        // 10000
    const int E = in_sizes[1] / 2;         // 320000
    const int Etot = E + N;

    char* base = (char*)d_ws;
    size_t off = 0;
    auto carve = [&](size_t bytes) {
        char* p = base + off;
        off = (off + bytes + 255) & ~(size_t)255;
        return p;
    };
    bf16_t* hbuf   = (bf16_t*)carve((size_t)N * 768 * 2);
    bf16_t* x1b    = (bf16_t*)carve((size_t)N * 256 * 2);
    bf16_t* x2b    = (bf16_t*)carve((size_t)N * 256 * 2);
    bf16_t* x3b    = (bf16_t*)carve((size_t)N * 768 * 2);
    bf16_t* Wt2    = (bf16_t*)carve((size_t)256 * 256 * 2);
    bf16_t* Wt3    = (bf16_t*)carve((size_t)256 * 768 * 2);
    float*  al     = (float*)carve((size_t)N * 12 * 4);
    float*  ar     = (float*)carve((size_t)N * 12 * 4);
    float*  alphab = (float*)carve((size_t)Etot * 12 * 4);
    int*    rowptr = (int*)carve((size_t)(N + 1) * 4);
    int*    cnt2   = (int*)carve((size_t)(2 * N) * 4);   // counts | cursor contiguous
    int*    counts = cnt2;
    int*    cursor = cnt2 + N;
    int*    esrc   = (int*)carve((size_t)Etot * 4);
    (void)ws_size;

    float* out1 = (float*)d_out;
    float* out2 = (float*)d_out + N;

    const int TB = 256;
    int eb = (Etot + TB - 1) / TB;
    int nodeblocks = (N + 3) / 4;          // 4 node-waves per block

    // --- CSR by dst + weight prep ---
    zero_i32<<<(2 * N + TB - 1) / TB, TB, 0, stream>>>(cnt2, 2 * N);
    count_edges<<<eb, TB, 0, stream>>>(ei, E, N, counts);
    scan_rowptr<<<1, 1024, 0, stream>>>(counts, rowptr, N);
    fill_edges<<<eb, TB, 0, stream>>>(ei, E, N, rowptr, cursor, esrc);
    transpose_cast2<<<dim3(16, 64), TB, 0, stream>>>(W2, Wt2, W3, Wt3);

    // --- layer 1: 16 -> 8x32 (fp32 gemm + fused scores) ---
    gemm_f32_sc<<<dim3(4, (N + 63) / 64), TB, 0, stream>>>(x, W1, hbuf, a1s, a1d, al, ar, N, 16, 256, 8);
    alpha_node<8><<<nodeblocks, TB, 0, stream>>>(al, ar, rowptr, esrc, alphab, N, Etot);
    gat_agg<256, 32><<<2 * nodeblocks, TB, 0, stream>>>(hbuf, alphab, rowptr, esrc, b1, x1b, N, Etot, nodeblocks);

    // --- layer 2: 256 -> 8x32 (MFMA + fused scores) ---
    gemm_mfma_sc<32><<<dim3(4, (N + 127) / 128), TB, 0, stream>>>(x1b, Wt2, hbuf, a2s, a2d, al, ar, N, 256, 256, 8);
    alpha_node<8><<<nodeblocks, TB, 0, stream>>>(al, ar, rowptr, esrc, alphab, N, Etot);
    gat_agg<256, 32><<<2 * nodeblocks, TB, 0, stream>>>(hbuf, alphab, rowptr, esrc, b2, x2b, N, Etot, nodeblocks);

    // --- layer 3: 256 -> 12x64 (MFMA + fused scores) ---
    gemm_mfma_sc<64><<<dim3(12, (N + 127) / 128), TB, 0, stream>>>(x2b, Wt3, hbuf, a3s, a3d, al, ar, N, 256, 768, 12);
    alpha_node<12><<<nodeblocks, TB, 0, stream>>>(al, ar, rowptr, esrc, alphab, N, Etot);
    gat_agg<768, 64><<<6 * nodeblocks, TB, 0, stream>>>(hbuf, alphab, rowptr, esrc, b3, x3b, N, Etot, nodeblocks);

    // --- fused final linear + MLP ---
    head_fused<<<nodeblocks, TB, 0, stream>>>(x, x1b, x2b, x3b, Wf, bf,
                                              M1w, M1b, M2w, M2b, M3w, M3b, out1, out2, N);
}

// Round 12
// 327.353 us; speedup vs baseline: 1.1025x; 1.0237x over previous
//
#include <hip/hip_runtime.h>
#include <math.h>

// ---------------------------------------------------------------------------
// GATNet (3x GATConv + final linear + MLP), MI355X.
// R11: agg inner loop in packed float2 (v_pk_fma_f32 path), alpha 2 nodes
// per wave (half-wave reductions), zero via hipMemsetAsync.
// Carried: fused-score GEMMs, agg v6 structure, L2-sliced groups, all-bf16.
// ---------------------------------------------------------------------------

typedef unsigned short bf16_t;
typedef __attribute__((ext_vector_type(8))) short bf16x8;
typedef __attribute__((ext_vector_type(4))) float f32x4;
typedef __attribute__((ext_vector_type(2))) float f32x2;

__device__ inline float bf2f(bf16_t u) {
    union { unsigned int i; float f; } v; v.i = ((unsigned int)u) << 16; return v.f;
}
__device__ inline float u2f(unsigned int x) {
    union { unsigned int i; float f; } v; v.i = x; return v.f;
}
__device__ inline bf16_t f2bf(float f) {
    union { float f; unsigned int i; } v; v.f = f;
    unsigned int r = v.i + 0x7FFF + ((v.i >> 16) & 1);   // round-nearest-even
    return (bf16_t)(r >> 16);
}

// ------------------------------ CSR build ----------------------------------

__global__ void count_edges(const int* __restrict__ ei, int E, int Nn,
                            int* __restrict__ counts) {
    int e = blockIdx.x * blockDim.x + threadIdx.x;
    if (e >= E + Nn) return;
    int dst = (e < E) ? ei[E + e] : (e - E);   // self-loops appended
    atomicAdd(&counts[dst], 1);
}

// single block, 1024 threads: serial-per-thread + shuffle block scan
__global__ __launch_bounds__(1024) void scan_rowptr(const int* __restrict__ counts,
                                                    int* __restrict__ rowptr, int n) {
    const int IPT = (n + 1023) / 1024;   // <=16
    int t = threadIdx.x;
    int base = t * IPT;
    int loc[16];
    int run = 0;
#pragma unroll
    for (int i = 0; i < 16; i++) {
        if (i >= IPT) break;
        int idx = base + i;
        int v = (idx < n) ? counts[idx] : 0;
        loc[i] = run;
        run += v;
    }
    int lane = t & 63, wid = t >> 6;
    int v = run;
    for (int off = 1; off < 64; off <<= 1) {
        int u = __shfl_up(v, off, 64);
        if (lane >= off) v += u;
    }
    __shared__ int wsum[16];
    __shared__ int woff[16];
    if (lane == 63) wsum[wid] = v;
    __syncthreads();
    if (t == 0) { int s = 0; for (int i = 0; i < 16; i++) { woff[i] = s; s += wsum[i]; } }
    __syncthreads();
    int excl = v - run + woff[wid];
#pragma unroll
    for (int i = 0; i < 16; i++) {
        if (i >= IPT) break;
        int idx = base + i;
        if (idx < n) rowptr[idx] = excl + loc[i];
    }
    if (t == 1023) rowptr[n] = excl + run;
}

__global__ void fill_edges(const int* __restrict__ ei, int E, int Nn,
                           const int* __restrict__ rowptr, int* __restrict__ cursor,
                           int* __restrict__ edge_src) {
    int e = blockIdx.x * blockDim.x + threadIdx.x;
    if (e >= E + Nn) return;
    int src, dst;
    if (e < E) { src = ei[e]; dst = ei[E + e]; }
    else       { src = e - E; dst = src; }
    int pos = atomicAdd(&cursor[dst], 1);
    edge_src[rowptr[dst] + pos] = src;
}

// ---------------------------------------------------------------------------
// Fused transpose+cast for both weight matrices (K=256 each).
// ---------------------------------------------------------------------------
__global__ __launch_bounds__(256) void transpose_cast2(const float* __restrict__ W2,
                                                       bf16_t* __restrict__ Wt2,
                                                       const float* __restrict__ W3,
                                                       bf16_t* __restrict__ Wt3) {
    __shared__ float tile[16][17];
    const float* W; bf16_t* Wt; int Nc, n0;
    if (blockIdx.y < 16) { W = W2; Wt = Wt2; Nc = 256; n0 = blockIdx.y * 16; }
    else                 { W = W3; Wt = Wt3; Nc = 768; n0 = (blockIdx.y - 16) * 16; }
    int k0 = blockIdx.x * 16;
    int tx = threadIdx.x & 15, ty = threadIdx.x >> 4;
    tile[ty][tx] = W[(size_t)(k0 + ty) * Nc + n0 + tx];
    __syncthreads();
    Wt[(size_t)(n0 + ty) * 256 + k0 + tx] = f2bf(tile[tx][ty]);
}

// ---------------------------------------------------------------------------
// fp32 GEMM (layer 1, K=16, C=32, H=8), bf16 out + fused al/ar scores.
// ---------------------------------------------------------------------------
__global__ __launch_bounds__(256) void gemm_f32_sc(const float* __restrict__ A,
                                                   const float* __restrict__ B,
                                                   bf16_t* __restrict__ Cm,
                                                   const float* __restrict__ a_s,
                                                   const float* __restrict__ a_d,
                                                   float* __restrict__ al,
                                                   float* __restrict__ ar,
                                                   int M, int K, int Nc, int H) {
    __shared__ float As[16][64];
    __shared__ float Bs[16][64];
    int t  = threadIdx.x;
    int tx = t & 15, ty = t >> 4;
    int row0 = blockIdx.y * 64, col0 = blockIdx.x * 64;
    int a_r = t >> 2, a_c = (t & 3) * 4;
    int b_r = t >> 4, b_c = (t & 15) * 4;

    float acc[4][4];
#pragma unroll
    for (int i = 0; i < 4; i++)
#pragma unroll
        for (int j = 0; j < 4; j++) acc[i][j] = 0.f;

    for (int kt = 0; kt < K; kt += 16) {
        float4 av = make_float4(0.f, 0.f, 0.f, 0.f);
        int gr = row0 + a_r;
        if (gr < M) av = *(const float4*)(A + (size_t)gr * K + kt + a_c);
        As[a_c + 0][a_r] = av.x;
        As[a_c + 1][a_r] = av.y;
        As[a_c + 2][a_r] = av.z;
        As[a_c + 3][a_r] = av.w;
        float4 bv = *(const float4*)(B + (size_t)(kt + b_r) * Nc + col0 + b_c);
        *(float4*)&Bs[b_r][b_c] = bv;
        __syncthreads();
#pragma unroll
        for (int k = 0; k < 16; k++) {
            float4 a4 = *(const float4*)&As[k][ty * 4];
            float4 b4 = *(const float4*)&Bs[k][tx * 4];
            float aa[4] = {a4.x, a4.y, a4.z, a4.w};
            float bb[4] = {b4.x, b4.y, b4.z, b4.w};
#pragma unroll
            for (int i = 0; i < 4; i++)
#pragma unroll
                for (int j = 0; j < 4; j++) acc[i][j] += aa[i] * bb[j];
        }
        __syncthreads();
    }
    float4 asv = *(const float4*)(a_s + col0 + tx * 4);
    float4 adv = *(const float4*)(a_d + col0 + tx * 4);
#pragma unroll
    for (int i = 0; i < 4; i++) {
        int gr = row0 + ty * 4 + i;
        float sa = acc[i][0] * asv.x + acc[i][1] * asv.y + acc[i][2] * asv.z + acc[i][3] * asv.w;
        float sd = acc[i][0] * adv.x + acc[i][1] * adv.y + acc[i][2] * adv.z + acc[i][3] * adv.w;
#pragma unroll
        for (int off = 4; off > 0; off >>= 1) {
            sa += __shfl_xor(sa, off, 64);
            sd += __shfl_xor(sd, off, 64);
        }
        if ((tx == 0 || tx == 8) && gr < M) {
            int h = (col0 >> 5) + (tx >> 3);
            al[gr * H + h] = sa;
            ar[gr * H + h] = sd;
        }
        if (gr < M) {
            ushort4 v;
            v.x = f2bf(acc[i][0]); v.y = f2bf(acc[i][1]);
            v.z = f2bf(acc[i][2]); v.w = f2bf(acc[i][3]);
            *(ushort4*)(Cm + (size_t)gr * Nc + col0 + tx * 4) = v;
        }
    }
}

// ---------------------------------------------------------------------------
// MFMA bf16 GEMM (layers 2/3) + fused al/ar scores (block-local, no atomics).
// ---------------------------------------------------------------------------
template <int C_>
__global__ __launch_bounds__(256) void gemm_mfma_sc(const bf16_t* __restrict__ A,
                                                    const bf16_t* __restrict__ Bt,
                                                    bf16_t* __restrict__ Cm,
                                                    const float* __restrict__ a_s,
                                                    const float* __restrict__ a_d,
                                                    float* __restrict__ al,
                                                    float* __restrict__ ar,
                                                    int M, int K, int Nc, int H) {
    int wave = threadIdx.x >> 6, lane = threadIdx.x & 63;
    int quad = lane >> 4, l16 = lane & 15;
    int m0 = blockIdx.y * 128 + wave * 32;
    int n0 = blockIdx.x * 64;

    f32x4 acc[2][4];
    f32x4 z = {0.f, 0.f, 0.f, 0.f};
#pragma unroll
    for (int i = 0; i < 2; i++)
#pragma unroll
        for (int j = 0; j < 4; j++) acc[i][j] = z;

    int r0 = m0 + l16;       if (r0 >= M) r0 = M - 1;
    int r1 = m0 + 16 + l16;  if (r1 >= M) r1 = M - 1;
    const bf16_t* Ap0 = A + (size_t)r0 * K + quad * 8;
    const bf16_t* Ap1 = A + (size_t)r1 * K + quad * 8;
    const bf16_t* Bp0 = Bt + (size_t)(n0 + 0  + l16) * K + quad * 8;
    const bf16_t* Bp1 = Bt + (size_t)(n0 + 16 + l16) * K + quad * 8;
    const bf16_t* Bp2 = Bt + (size_t)(n0 + 32 + l16) * K + quad * 8;
    const bf16_t* Bp3 = Bt + (size_t)(n0 + 48 + l16) * K + quad * 8;

    for (int kt = 0; kt < K; kt += 32) {
        bf16x8 a0 = *(const bf16x8*)(Ap0 + kt);
        bf16x8 a1 = *(const bf16x8*)(Ap1 + kt);
        bf16x8 b0 = *(const bf16x8*)(Bp0 + kt);
        bf16x8 b1 = *(const bf16x8*)(Bp1 + kt);
        bf16x8 b2 = *(const bf16x8*)(Bp2 + kt);
        bf16x8 b3 = *(const bf16x8*)(Bp3 + kt);
        acc[0][0] = __builtin_amdgcn_mfma_f32_16x16x32_bf16(a0, b0, acc[0][0], 0, 0, 0);
        acc[1][0] = __builtin_amdgcn_mfma_f32_16x16x32_bf16(a1, b0, acc[1][0], 0, 0, 0);
        acc[0][1] = __builtin_amdgcn_mfma_f32_16x16x32_bf16(a0, b1, acc[0][1], 0, 0, 0);
        acc[1][1] = __builtin_amdgcn_mfma_f32_16x16x32_bf16(a1, b1, acc[1][1], 0, 0, 0);
        acc[0][2] = __builtin_amdgcn_mfma_f32_16x16x32_bf16(a0, b2, acc[0][2], 0, 0, 0);
        acc[1][2] = __builtin_amdgcn_mfma_f32_16x16x32_bf16(a1, b2, acc[1][2], 0, 0, 0);
        acc[0][3] = __builtin_amdgcn_mfma_f32_16x16x32_bf16(a0, b3, acc[0][3], 0, 0, 0);
        acc[1][3] = __builtin_amdgcn_mfma_f32_16x16x32_bf16(a1, b3, acc[1][3], 0, 0, 0);
    }

    float asv[4], adv[4];
#pragma unroll
    for (int j = 0; j < 4; j++) {
        asv[j] = a_s[n0 + j * 16 + l16];
        adv[j] = a_d[n0 + j * 16 + l16];
    }
#pragma unroll
    for (int i = 0; i < 2; i++)
#pragma unroll
        for (int r = 0; r < 4; r++) {
            int gr = m0 + i * 16 + quad * 4 + r;
            if (C_ == 64) {
                float sa = acc[i][0][r] * asv[0] + acc[i][1][r] * asv[1]
                         + acc[i][2][r] * asv[2] + acc[i][3][r] * asv[3];
                float sd = acc[i][0][r] * adv[0] + acc[i][1][r] * adv[1]
                         + acc[i][2][r] * adv[2] + acc[i][3][r] * adv[3];
#pragma unroll
                for (int off = 8; off > 0; off >>= 1) {
                    sa += __shfl_xor(sa, off, 64);
                    sd += __shfl_xor(sd, off, 64);
                }
                if (l16 == 0 && gr < M) {
                    int h = n0 >> 6;
                    al[gr * H + h] = sa;
                    ar[gr * H + h] = sd;
                }
            } else {
                float saA = acc[i][0][r] * asv[0] + acc[i][1][r] * asv[1];
                float saB = acc[i][2][r] * asv[2] + acc[i][3][r] * asv[3];
                float sdA = acc[i][0][r] * adv[0] + acc[i][1][r] * adv[1];
                float sdB = acc[i][2][r] * adv[2] + acc[i][3][r] * adv[3];
#pragma unroll
                for (int off = 8; off > 0; off >>= 1) {
                    saA += __shfl_xor(saA, off, 64);
                    saB += __shfl_xor(saB, off, 64);
                    sdA += __shfl_xor(sdA, off, 64);
                    sdB += __shfl_xor(sdB, off, 64);
                }
                if (l16 == 0 && gr < M) {
                    int h = n0 >> 5;
                    al[gr * H + h]     = saA;
                    ar[gr * H + h]     = sdA;
                    al[gr * H + h + 1] = saB;
                    ar[gr * H + h + 1] = sdB;
                }
            }
        }
#pragma unroll
    for (int i = 0; i < 2; i++)
#pragma unroll
        for (int j = 0; j < 4; j++)
#pragma unroll
            for (int r = 0; r < 4; r++) {
                int gr = m0 + i * 16 + quad * 4 + r;
                if (gr < M) Cm[(size_t)gr * Nc + n0 + j * 16 + l16] = f2bf(acc[i][j][r]);
            }
}

// ---------------------------------------------------------------------------
// alpha v3: HALF-wave per node (2 nodes/wave — mean deg 33 < 64 wasted half
// the lanes). Register p covers deg<=64; guarded tail beyond; xor-reductions
// stay within each 32-lane half; planar [head][edge] stores.
// ---------------------------------------------------------------------------
template <int H>
__global__ __launch_bounds__(256) void alpha_node(const float* __restrict__ al,
                                                  const float* __restrict__ ar,
                                                  const int* __restrict__ rowptr,
                                                  const int* __restrict__ esrc,
                                                  float* __restrict__ alpha,
                                                  int n, int Etot) {
    int pair = (blockIdx.x * blockDim.x + threadIdx.x) >> 6;   // wave id
    int lane = threadIdx.x & 63;
    int node = pair * 2 + (lane >> 5);
    if (node >= n) return;
    int lane32 = lane & 31;

    float arv[H];
#pragma unroll
    for (int h4 = 0; h4 < H; h4 += 4) {
        float4 t = *(const float4*)(ar + (size_t)node * H + h4);
        arv[h4] = t.x; arv[h4 + 1] = t.y; arv[h4 + 2] = t.z; arv[h4 + 3] = t.w;
    }
    int beg = rowptr[node], end = rowptr[node + 1];
    float p0[H], p1[H], s[H];
#pragma unroll
    for (int h = 0; h < H; h++) { p0[h] = 0.f; p1[h] = 0.f; s[h] = 0.f; }

    int j0 = beg + lane32;
    if (j0 < end) {
        const float* alr = al + (size_t)esrc[j0] * H;
#pragma unroll
        for (int h4 = 0; h4 < H; h4 += 4) {
            float4 t = *(const float4*)(alr + h4);
            float e;
            e = t.x + arv[h4];     e = fmaxf(e, 0.2f * e); p0[h4]     = __expf(fminf(e, 60.f));
            e = t.y + arv[h4 + 1]; e = fmaxf(e, 0.2f * e); p0[h4 + 1] = __expf(fminf(e, 60.f));
            e = t.z + arv[h4 + 2]; e = fmaxf(e, 0.2f * e); p0[h4 + 2] = __expf(fminf(e, 60.f));
            e = t.w + arv[h4 + 3]; e = fmaxf(e, 0.2f * e); p0[h4 + 3] = __expf(fminf(e, 60.f));
        }
#pragma unroll
        for (int h = 0; h < H; h++) s[h] += p0[h];
    }
    int j1 = j0 + 32;
    if (j1 < end) {
        const float* alr = al + (size_t)esrc[j1] * H;
#pragma unroll
        for (int h4 = 0; h4 < H; h4 += 4) {
            float4 t = *(const float4*)(alr + h4);
            float e;
            e = t.x + arv[h4];     e = fmaxf(e, 0.2f * e); p1[h4]     = __expf(fminf(e, 60.f));
            e = t.y + arv[h4 + 1]; e = fmaxf(e, 0.2f * e); p1[h4 + 1] = __expf(fminf(e, 60.f));
            e = t.z + arv[h4 + 2]; e = fmaxf(e, 0.2f * e); p1[h4 + 2] = __expf(fminf(e, 60.f));
            e = t.w + arv[h4 + 3]; e = fmaxf(e, 0.2f * e); p1[h4 + 3] = __expf(fminf(e, 60.f));
        }
#pragma unroll
        for (int h = 0; h < H; h++) s[h] += p1[h];
    }
    for (int j = j0 + 64; j < end; j += 32) {
        const float* alr = al + (size_t)esrc[j] * H;
#pragma unroll
        for (int h = 0; h < H; h++) {
            float e = alr[h] + arv[h];
            e = fmaxf(e, 0.2f * e);
            float p = __expf(fminf(e, 60.f));
            alpha[(size_t)h * Etot + j] = p;
            s[h] += p;
        }
    }
#pragma unroll
    for (int h = 0; h < H; h++) {
        float v = s[h];
#pragma unroll
        for (int off = 16; off > 0; off >>= 1) v += __shfl_xor(v, off, 64);  // within 32-half
        s[h] = 1.f / v;
    }
    if (j0 < end) {
#pragma unroll
        for (int h = 0; h < H; h++) alpha[(size_t)h * Etot + j0] = p0[h] * s[h];
    }
    if (j1 < end) {
#pragma unroll
        for (int h = 0; h < H; h++) alpha[(size_t)h * Etot + j1] = p1[h] * s[h];
    }
    for (int j = j0 + 64; j < end; j += 32) {
#pragma unroll
        for (int h = 0; h < H; h++) alpha[(size_t)h * Etot + j] *= s[h];
    }
}

// ---------------------------------------------------------------------------
// agg v6.1: v6 structure with packed-float2 accumulate (v_pk_fma_f32 path).
// Wave per (node, 128-ch group); preloaded indices + bpermute; depth-2
// pipelined 8-edge packs; direct-load stride-4 tail.
// ---------------------------------------------------------------------------
template <int HC_, int C>
__global__ __launch_bounds__(256) void gat_agg(
    const bf16_t* __restrict__ hbuf, const float* __restrict__ alpha,
    const int* __restrict__ rowptr, const int* __restrict__ esrc,
    const float* __restrict__ bias, bf16_t* __restrict__ outb,
    int n, int Etot, int nodeblocks) {
    int group = blockIdx.x / nodeblocks;
    int nb    = blockIdx.x - group * nodeblocks;
    int node  = nb * 4 + (threadIdx.x >> 6);
    if (node >= n) return;
    int lane = threadIdx.x & 63;
    int sub  = lane >> 4;          // edge slot 0..3
    int cl   = lane & 15;          // channel slot 0..15
    int gc   = group * 128 + cl * 8;
    int head = gc / C;
    const bf16_t* hb = hbuf + gc;
    const float*  ap = alpha + (size_t)head * Etot;

    f32x2 acc2[4];
    f32x2 z2 = {0.f, 0.f};
#pragma unroll
    for (int i = 0; i < 4; i++) acc2[i] = z2;

    int beg = rowptr[node], end = rowptr[node + 1];
    int deg = end - beg;

    int e0 = 0, e1 = 0;
    {
        int i0 = beg + lane;
        if (i0 < end) e0 = esrc[i0];
        int i1 = beg + 64 + lane;
        if (i1 < end) e1 = esrc[i1];
    }
    int npre  = deg < 128 ? deg : 128;
    int nfull = npre >> 3;         // 8-edge packs from preloaded region

    if (nfull > 0) {
        int s0 = __shfl(e0, sub, 64);
        int s1 = __shfl(e0, sub + 4, 64);
        float a0 = ap[beg + sub], a1 = ap[beg + sub + 4];
        bf16x8 u0 = *(const bf16x8*)(hb + (size_t)s0 * HC_);
        bf16x8 u1 = *(const bf16x8*)(hb + (size_t)s1 * HC_);
        for (int it = 1; it < nfull; ++it) {
            int kb = it * 8;
            int esel = (kb < 64) ? e0 : e1;
            int t0 = __shfl(esel, (kb + sub) & 63, 64);
            int t1 = __shfl(esel, (kb + sub + 4) & 63, 64);
            float b0v = ap[beg + kb + sub], b1v = ap[beg + kb + sub + 4];
            bf16x8 v0 = *(const bf16x8*)(hb + (size_t)t0 * HC_);
            bf16x8 v1 = *(const bf16x8*)(hb + (size_t)t1 * HC_);
            const unsigned int* d0 = (const unsigned int*)&u0;
            const unsigned int* d1 = (const unsigned int*)&u1;
            f32x2 a0v = {a0, a0}, a1v = {a1, a1};
#pragma unroll
            for (int i = 0; i < 4; i++) {
                f32x2 w0 = {u2f(d0[i] << 16), u2f(d0[i] & 0xffff0000u)};
                f32x2 w1 = {u2f(d1[i] << 16), u2f(d1[i] & 0xffff0000u)};
                acc2[i] += a0v * w0;
                acc2[i] += a1v * w1;
            }
            u0 = v0; u1 = v1; a0 = b0v; a1 = b1v;
        }
        const unsigned int* d0 = (const unsigned int*)&u0;
        const unsigned int* d1 = (const unsigned int*)&u1;
        f32x2 a0v = {a0, a0}, a1v = {a1, a1};
#pragma unroll
        for (int i = 0; i < 4; i++) {
            f32x2 w0 = {u2f(d0[i] << 16), u2f(d0[i] & 0xffff0000u)};
            f32x2 w1 = {u2f(d1[i] << 16), u2f(d1[i] & 0xffff0000u)};
            acc2[i] += a0v * w0;
            acc2[i] += a1v * w1;
        }
    }
    for (int j = beg + (nfull << 3) + sub; j < end; j += 4) {
        int s0 = esrc[j];
        float a0 = ap[j];
        bf16x8 u0 = *(const bf16x8*)(hb + (size_t)s0 * HC_);
        const unsigned int* d0 = (const unsigned int*)&u0;
        f32x2 a0v = {a0, a0};
#pragma unroll
        for (int i = 0; i < 4; i++) {
            f32x2 w0 = {u2f(d0[i] << 16), u2f(d0[i] & 0xffff0000u)};
            acc2[i] += a0v * w0;
        }
    }
    float acc[8] = {acc2[0].x, acc2[0].y, acc2[1].x, acc2[1].y,
                    acc2[2].x, acc2[2].y, acc2[3].x, acc2[3].y};
#pragma unroll
    for (int i = 0; i < 8; i++) {
        acc[i] += __shfl_xor(acc[i], 16, 64);
        acc[i] += __shfl_xor(acc[i], 32, 64);
    }
    if (sub == 0) {
        float4 b0 = *(const float4*)(bias + gc);
        float4 b1 = *(const float4*)(bias + gc + 4);
        float bb[8] = {b0.x, b0.y, b0.z, b0.w, b1.x, b1.y, b1.z, b1.w};
        bf16x8 outv;
        unsigned short* ov = (unsigned short*)&outv;
#pragma unroll
        for (int i = 0; i < 8; i++) ov[i] = f2bf(fmaxf(acc[i] + bb[i], 0.f));
        *(bf16x8*)(outb + (size_t)node * HC_ + gc) = outv;
    }
}

// ---------------------------------------------------------------------------
// Fused head: out1 = sigmoid(concat(x1,x2,x3).Wf + bf); then MLP -> out2.
// ---------------------------------------------------------------------------
__global__ __launch_bounds__(256) void head_fused(
    const float* __restrict__ x, const bf16_t* __restrict__ x1b,
    const bf16_t* __restrict__ x2b, const bf16_t* __restrict__ x3b,
    const float* __restrict__ Wf, const float* __restrict__ bfc,
    const float* __restrict__ M1w, const float* __restrict__ M1b,
    const float* __restrict__ M2w, const float* __restrict__ M2b,
    const float* __restrict__ M3w, const float* __restrict__ M3b,
    float* __restrict__ out1, float* __restrict__ out2, int n) {
    __shared__ float h1s[4][128];
    int w    = threadIdx.x >> 6;
    int lane = threadIdx.x & 63;
    int node = blockIdx.x * 4 + w;
    bool valid = node < n;
    int nd = valid ? node : 0;

    float s = 0.f;
    {
        ushort4 u = *(const ushort4*)(x1b + (size_t)nd * 256 + lane * 4);
        const float* wv = Wf + lane * 4;
        s += bf2f(u.x) * wv[0] + bf2f(u.y) * wv[1] + bf2f(u.z) * wv[2] + bf2f(u.w) * wv[3];
    }
    {
        ushort4 u = *(const ushort4*)(x2b + (size_t)nd * 256 + lane * 4);
        const float* wv = Wf + 256 + lane * 4;
        s += bf2f(u.x) * wv[0] + bf2f(u.y) * wv[1] + bf2f(u.z) * wv[2] + bf2f(u.w) * wv[3];
    }
#pragma unroll
    for (int i = 0; i < 3; i++) {
        int k = i * 256 + lane * 4;
        ushort4 u = *(const ushort4*)(x3b + (size_t)nd * 768 + k);
        const float* wv = Wf + 512 + k;
        s += bf2f(u.x) * wv[0] + bf2f(u.y) * wv[1] + bf2f(u.z) * wv[2] + bf2f(u.w) * wv[3];
    }
#pragma unroll
    for (int off = 32; off > 0; off >>= 1) s += __shfl_xor(s, off, 64);
    float so = 1.f / (1.f + __expf(-(s + bfc[0])));
    if (lane == 0 && valid) out1[node] = so;

    float xm[17];
#pragma unroll
    for (int k = 0; k < 16; k++) xm[k] = x[nd * 16 + k];
    xm[16] = so;

    float a0 = M1b[lane], a1 = M1b[lane + 64];
#pragma unroll
    for (int k = 0; k < 17; k++) {
        a0 += xm[k] * M1w[k * 128 + lane];
        a1 += xm[k] * M1w[k * 128 + lane + 64];
    }
    h1s[w][lane]      = fmaxf(a0, 0.f);
    h1s[w][lane + 64] = fmaxf(a1, 0.f);
    __syncthreads();

    float b0 = M2b[lane];
#pragma unroll 16
    for (int k = 0; k < 128; k++) b0 += h1s[w][k] * M2w[k * 64 + lane];
    b0 = fmaxf(b0, 0.f);

    float p = b0 * M3w[lane];
#pragma unroll
    for (int off = 32; off > 0; off >>= 1) p += __shfl_xor(p, off, 64);
    if (lane == 0 && valid) out2[node] = 1.f / (1.f + __expf(-(p + M3b[0])));
}

// ---------------------------------------------------------------------------
extern "C" void kernel_launch(void* const* d_in, const int* in_sizes, int n_in,
                              void* d_out, int out_size, void* d_ws, size_t ws_size,
                              hipStream_t stream) {
    const float* x   = (const float*)d_in[0];
    const int*   ei  = (const int*)d_in[1];
    const float* W1  = (const float*)d_in[3];
    const float* a1s = (const float*)d_in[4];
    const float* a1d = (const float*)d_in[5];
    const float* b1  = (const float*)d_in[6];
    const float* W2  = (const float*)d_in[7];
    const float* a2s = (const float*)d_in[8];
    const float* a2d = (const float*)d_in[9];
    const float* b2  = (const float*)d_in[10];
    const float* W3  = (const float*)d_in[11];
    const float* a3s = (const float*)d_in[12];
    const float* a3d = (const float*)d_in[13];
    const float* b3  = (const float*)d_in[14];
    const float* Wf  = (const float*)d_in[15];
    const float* bf  = (const float*)d_in[16];
    const float* M1w = (const float*)d_in[17];
    const float* M1b = (const float*)d_in[18];
    const float* M2w = (const float*)d_in[19];
    const float* M2b = (const float*)d_in[20];
    const float* M3w = (const float*)d_in[21];
    const float* M3b = (const float*)d_in[22];

    const int N = in_sizes[0] / 16;        // 10000
    const int E = in_sizes[1] / 2;         // 320000
    const int Etot = E + N;

    char* base = (char*)d_ws;
    size_t off = 0;
    auto carve = [&](size_t bytes) {
        char* p = base + off;
        off = (off + bytes + 255) & ~(size_t)255;
        return p;
    };
    bf16_t* hbuf   = (bf16_t*)carve((size_t)N * 768 * 2);
    bf16_t* x1b    = (bf16_t*)carve((size_t)N * 256 * 2);
    bf16_t* x2b    = (bf16_t*)carve((size_t)N * 256 * 2);
    bf16_t* x3b    = (bf16_t*)carve((size_t)N * 768 * 2);
    bf16_t* Wt2    = (bf16_t*)carve((size_t)256 * 256 * 2);
    bf16_t* Wt3    = (bf16_t*)carve((size_t)256 * 768 * 2);
    float*  al     = (float*)carve((size_t)N * 12 * 4);
    float*  ar     = (float*)carve((size_t)N * 12 * 4);
    float*  alphab = (float*)carve((size_t)Etot * 12 * 4);
    int*    rowptr = (int*)carve((size_t)(N + 1) * 4);
    int*    cnt2   = (int*)carve((size_t)(2 * N) * 4);   // counts | cursor contiguous
    int*    counts = cnt2;
    int*    cursor = cnt2 + N;
    int*    esrc   = (int*)carve((size_t)Etot * 4);
    (void)ws_size;

    float* out1 = (float*)d_out;
    float* out2 = (float*)d_out + N;

    const int TB = 256;
    int eb = (Etot + TB - 1) / TB;
    int nodeblocks = (N + 3) / 4;          // 4 node-waves per block
    int alphablocks = (N + 7) / 8;         // 2 nodes per wave, 4 waves/block

    // --- CSR by dst + weight prep ---
    hipMemsetAsync(cnt2, 0, (size_t)(2 * N) * 4, stream);
    count_edges<<<eb, TB, 0, stream>>>(ei, E, N, counts);
    scan_rowptr<<<1, 1024, 0, stream>>>(counts, rowptr, N);
    fill_edges<<<eb, TB, 0, stream>>>(ei, E, N, rowptr, cursor, esrc);
    transpose_cast2<<<dim3(16, 64), TB, 0, stream>>>(W2, Wt2, W3, Wt3);

    // --- layer 1: 16 -> 8x32 (fp32 gemm + fused scores) ---
    gemm_f32_sc<<<dim3(4, (N + 63) / 64), TB, 0, stream>>>(x, W1, hbuf, a1s, a1d, al, ar, N, 16, 256, 8);
    alpha_node<8><<<alphablocks, TB, 0, stream>>>(al, ar, rowptr, esrc, alphab, N, Etot);
    gat_agg<256, 32><<<2 * nodeblocks, TB, 0, stream>>>(hbuf, alphab, rowptr, esrc, b1, x1b, N, Etot, nodeblocks);

    // --- layer 2: 256 -> 8x32 (MFMA + fused scores) ---
    gemm_mfma_sc<32><<<dim3(4, (N + 127) / 128), TB, 0, stream>>>(x1b, Wt2, hbuf, a2s, a2d, al, ar, N, 256, 256, 8);
    alpha_node<8><<<alphablocks, TB, 0, stream>>>(al, ar, rowptr, esrc, alphab, N, Etot);
    gat_agg<256, 32><<<2 * nodeblocks, TB, 0, stream>>>(hbuf, alphab, rowptr, esrc, b2, x2b, N, Etot, nodeblocks);

    // --- layer 3: 256 -> 12x64 (MFMA + fused scores) ---
    gemm_mfma_sc<64><<<dim3(12, (N + 127) / 128), TB, 0, stream>>>(x2b, Wt3, hbuf, a3s, a3d, al, ar, N, 256, 768, 12);
    alpha_node<12><<<alphablocks, TB, 0, stream>>>(al, ar, rowptr, esrc, alphab, N, Etot);
    gat_agg<768, 64><<<6 * nodeblocks, TB, 0, stream>>>(hbuf, alphab, rowptr, esrc, b3, x3b, N, Etot, nodeblocks);

    // --- fused final linear + MLP ---
    head_fused<<<nodeblocks, TB, 0, stream>>>(x, x1b, x2b, x3b, Wf, bf,
                                              M1w, M1b, M2w, M2b, M3w, M3b, out1, out2, N);
}

// Round 13
// 312.676 us; speedup vs baseline: 1.1542x; 1.0469x over previous
//
#include <hip/hip_runtime.h>
#include <math.h>

// ---------------------------------------------------------------------------
// GATNet (3x GATConv + final linear + MLP), MI355X.
// R12: softmax fused INTO agg (v8): channel-groups partition heads, so each
// agg wave computes its own heads' alpha (pass 1: scores->p in wave LDS,
// per-head s) then gathers (pass 2: alpha via LDS read, 1/s folded into a
// single end multiply). Removes alpha_node dispatches + alphab round-trip.
// Carried: fused-score GEMMs, pk-fma accumulate, preloaded-index pipeline.
// ---------------------------------------------------------------------------

typedef unsigned short bf16_t;
typedef __attribute__((ext_vector_type(8))) short bf16x8;
typedef __attribute__((ext_vector_type(4))) float f32x4;
typedef __attribute__((ext_vector_type(2))) float f32x2;

__device__ inline float bf2f(bf16_t u) {
    union { unsigned int i; float f; } v; v.i = ((unsigned int)u) << 16; return v.f;
}
__device__ inline float u2f(unsigned int x) {
    union { unsigned int i; float f; } v; v.i = x; return v.f;
}
__device__ inline bf16_t f2bf(float f) {
    union { float f; unsigned int i; } v; v.f = f;
    unsigned int r = v.i + 0x7FFF + ((v.i >> 16) & 1);   // round-nearest-even
    return (bf16_t)(r >> 16);
}

// ------------------------------ CSR build ----------------------------------

__global__ void count_edges(const int* __restrict__ ei, int E, int Nn,
                            int* __restrict__ counts) {
    int e = blockIdx.x * blockDim.x + threadIdx.x;
    if (e >= E + Nn) return;
    int dst = (e < E) ? ei[E + e] : (e - E);   // self-loops appended
    atomicAdd(&counts[dst], 1);
}

// single block, 1024 threads: serial-per-thread + shuffle block scan
__global__ __launch_bounds__(1024) void scan_rowptr(const int* __restrict__ counts,
                                                    int* __restrict__ rowptr, int n) {
    const int IPT = (n + 1023) / 1024;   // <=16
    int t = threadIdx.x;
    int base = t * IPT;
    int loc[16];
    int run = 0;
#pragma unroll
    for (int i = 0; i < 16; i++) {
        if (i >= IPT) break;
        int idx = base + i;
        int v = (idx < n) ? counts[idx] : 0;
        loc[i] = run;
        run += v;
    }
    int lane = t & 63, wid = t >> 6;
    int v = run;
    for (int off = 1; off < 64; off <<= 1) {
        int u = __shfl_up(v, off, 64);
        if (lane >= off) v += u;
    }
    __shared__ int wsum[16];
    __shared__ int woff[16];
    if (lane == 63) wsum[wid] = v;
    __syncthreads();
    if (t == 0) { int s = 0; for (int i = 0; i < 16; i++) { woff[i] = s; s += wsum[i]; } }
    __syncthreads();
    int excl = v - run + woff[wid];
#pragma unroll
    for (int i = 0; i < 16; i++) {
        if (i >= IPT) break;
        int idx = base + i;
        if (idx < n) rowptr[idx] = excl + loc[i];
    }
    if (t == 1023) rowptr[n] = excl + run;
}

__global__ void fill_edges(const int* __restrict__ ei, int E, int Nn,
                           const int* __restrict__ rowptr, int* __restrict__ cursor,
                           int* __restrict__ edge_src) {
    int e = blockIdx.x * blockDim.x + threadIdx.x;
    if (e >= E + Nn) return;
    int src, dst;
    if (e < E) { src = ei[e]; dst = ei[E + e]; }
    else       { src = e - E; dst = src; }
    int pos = atomicAdd(&cursor[dst], 1);
    edge_src[rowptr[dst] + pos] = src;
}

// ---------------------------------------------------------------------------
// Fused transpose+cast for both weight matrices (K=256 each).
// ---------------------------------------------------------------------------
__global__ __launch_bounds__(256) void transpose_cast2(const float* __restrict__ W2,
                                                       bf16_t* __restrict__ Wt2,
                                                       const float* __restrict__ W3,
                                                       bf16_t* __restrict__ Wt3) {
    __shared__ float tile[16][17];
    const float* W; bf16_t* Wt; int Nc, n0;
    if (blockIdx.y < 16) { W = W2; Wt = Wt2; Nc = 256; n0 = blockIdx.y * 16; }
    else                 { W = W3; Wt = Wt3; Nc = 768; n0 = (blockIdx.y - 16) * 16; }
    int k0 = blockIdx.x * 16;
    int tx = threadIdx.x & 15, ty = threadIdx.x >> 4;
    tile[ty][tx] = W[(size_t)(k0 + ty) * Nc + n0 + tx];
    __syncthreads();
    Wt[(size_t)(n0 + ty) * 256 + k0 + tx] = f2bf(tile[tx][ty]);
}

// ---------------------------------------------------------------------------
// fp32 GEMM (layer 1, K=16, C=32, H=8), bf16 out + fused al/ar scores.
// ---------------------------------------------------------------------------
__global__ __launch_bounds__(256) void gemm_f32_sc(const float* __restrict__ A,
                                                   const float* __restrict__ B,
                                                   bf16_t* __restrict__ Cm,
                                                   const float* __restrict__ a_s,
                                                   const float* __restrict__ a_d,
                                                   float* __restrict__ al,
                                                   float* __restrict__ ar,
                                                   int M, int K, int Nc, int H) {
    __shared__ float As[16][64];
    __shared__ float Bs[16][64];
    int t  = threadIdx.x;
    int tx = t & 15, ty = t >> 4;
    int row0 = blockIdx.y * 64, col0 = blockIdx.x * 64;
    int a_r = t >> 2, a_c = (t & 3) * 4;
    int b_r = t >> 4, b_c = (t & 15) * 4;

    float acc[4][4];
#pragma unroll
    for (int i = 0; i < 4; i++)
#pragma unroll
        for (int j = 0; j < 4; j++) acc[i][j] = 0.f;

    for (int kt = 0; kt < K; kt += 16) {
        float4 av = make_float4(0.f, 0.f, 0.f, 0.f);
        int gr = row0 + a_r;
        if (gr < M) av = *(const float4*)(A + (size_t)gr * K + kt + a_c);
        As[a_c + 0][a_r] = av.x;
        As[a_c + 1][a_r] = av.y;
        As[a_c + 2][a_r] = av.z;
        As[a_c + 3][a_r] = av.w;
        float4 bv = *(const float4*)(B + (size_t)(kt + b_r) * Nc + col0 + b_c);
        *(float4*)&Bs[b_r][b_c] = bv;
        __syncthreads();
#pragma unroll
        for (int k = 0; k < 16; k++) {
            float4 a4 = *(const float4*)&As[k][ty * 4];
            float4 b4 = *(const float4*)&Bs[k][tx * 4];
            float aa[4] = {a4.x, a4.y, a4.z, a4.w};
            float bb[4] = {b4.x, b4.y, b4.z, b4.w};
#pragma unroll
            for (int i = 0; i < 4; i++)
#pragma unroll
                for (int j = 0; j < 4; j++) acc[i][j] += aa[i] * bb[j];
        }
        __syncthreads();
    }
    float4 asv = *(const float4*)(a_s + col0 + tx * 4);
    float4 adv = *(const float4*)(a_d + col0 + tx * 4);
#pragma unroll
    for (int i = 0; i < 4; i++) {
        int gr = row0 + ty * 4 + i;
        float sa = acc[i][0] * asv.x + acc[i][1] * asv.y + acc[i][2] * asv.z + acc[i][3] * asv.w;
        float sd = acc[i][0] * adv.x + acc[i][1] * adv.y + acc[i][2] * adv.z + acc[i][3] * adv.w;
#pragma unroll
        for (int off = 4; off > 0; off >>= 1) {
            sa += __shfl_xor(sa, off, 64);
            sd += __shfl_xor(sd, off, 64);
        }
        if ((tx == 0 || tx == 8) && gr < M) {
            int h = (col0 >> 5) + (tx >> 3);
            al[gr * H + h] = sa;
            ar[gr * H + h] = sd;
        }
        if (gr < M) {
            ushort4 v;
            v.x = f2bf(acc[i][0]); v.y = f2bf(acc[i][1]);
            v.z = f2bf(acc[i][2]); v.w = f2bf(acc[i][3]);
            *(ushort4*)(Cm + (size_t)gr * Nc + col0 + tx * 4) = v;
        }
    }
}

// ---------------------------------------------------------------------------
// MFMA bf16 GEMM (layers 2/3) + fused al/ar scores (block-local, no atomics).
// ---------------------------------------------------------------------------
template <int C_>
__global__ __launch_bounds__(256) void gemm_mfma_sc(const bf16_t* __restrict__ A,
                                                    const bf16_t* __restrict__ Bt,
                                                    bf16_t* __restrict__ Cm,
                                                    const float* __restrict__ a_s,
                                                    const float* __restrict__ a_d,
                                                    float* __restrict__ al,
                                                    float* __restrict__ ar,
                                                    int M, int K, int Nc, int H) {
    int wave = threadIdx.x >> 6, lane = threadIdx.x & 63;
    int quad = lane >> 4, l16 = lane & 15;
    int m0 = blockIdx.y * 128 + wave * 32;
    int n0 = blockIdx.x * 64;

    f32x4 acc[2][4];
    f32x4 z = {0.f, 0.f, 0.f, 0.f};
#pragma unroll
    for (int i = 0; i < 2; i++)
#pragma unroll
        for (int j = 0; j < 4; j++) acc[i][j] = z;

    int r0 = m0 + l16;       if (r0 >= M) r0 = M - 1;
    int r1 = m0 + 16 + l16;  if (r1 >= M) r1 = M - 1;
    const bf16_t* Ap0 = A + (size_t)r0 * K + quad * 8;
    const bf16_t* Ap1 = A + (size_t)r1 * K + quad * 8;
    const bf16_t* Bp0 = Bt + (size_t)(n0 + 0  + l16) * K + quad * 8;
    const bf16_t* Bp1 = Bt + (size_t)(n0 + 16 + l16) * K + quad * 8;
    const bf16_t* Bp2 = Bt + (size_t)(n0 + 32 + l16) * K + quad * 8;
    const bf16_t* Bp3 = Bt + (size_t)(n0 + 48 + l16) * K + quad * 8;

    for (int kt = 0; kt < K; kt += 32) {
        bf16x8 a0 = *(const bf16x8*)(Ap0 + kt);
        bf16x8 a1 = *(const bf16x8*)(Ap1 + kt);
        bf16x8 b0 = *(const bf16x8*)(Bp0 + kt);
        bf16x8 b1 = *(const bf16x8*)(Bp1 + kt);
        bf16x8 b2 = *(const bf16x8*)(Bp2 + kt);
        bf16x8 b3 = *(const bf16x8*)(Bp3 + kt);
        acc[0][0] = __builtin_amdgcn_mfma_f32_16x16x32_bf16(a0, b0, acc[0][0], 0, 0, 0);
        acc[1][0] = __builtin_amdgcn_mfma_f32_16x16x32_bf16(a1, b0, acc[1][0], 0, 0, 0);
        acc[0][1] = __builtin_amdgcn_mfma_f32_16x16x32_bf16(a0, b1, acc[0][1], 0, 0, 0);
        acc[1][1] = __builtin_amdgcn_mfma_f32_16x16x32_bf16(a1, b1, acc[1][1], 0, 0, 0);
        acc[0][2] = __builtin_amdgcn_mfma_f32_16x16x32_bf16(a0, b2, acc[0][2], 0, 0, 0);
        acc[1][2] = __builtin_amdgcn_mfma_f32_16x16x32_bf16(a1, b2, acc[1][2], 0, 0, 0);
        acc[0][3] = __builtin_amdgcn_mfma_f32_16x16x32_bf16(a0, b3, acc[0][3], 0, 0, 0);
        acc[1][3] = __builtin_amdgcn_mfma_f32_16x16x32_bf16(a1, b3, acc[1][3], 0, 0, 0);
    }

    float asv[4], adv[4];
#pragma unroll
    for (int j = 0; j < 4; j++) {
        asv[j] = a_s[n0 + j * 16 + l16];
        adv[j] = a_d[n0 + j * 16 + l16];
    }
#pragma unroll
    for (int i = 0; i < 2; i++)
#pragma unroll
        for (int r = 0; r < 4; r++) {
            int gr = m0 + i * 16 + quad * 4 + r;
            if (C_ == 64) {
                float sa = acc[i][0][r] * asv[0] + acc[i][1][r] * asv[1]
                         + acc[i][2][r] * asv[2] + acc[i][3][r] * asv[3];
                float sd = acc[i][0][r] * adv[0] + acc[i][1][r] * adv[1]
                         + acc[i][2][r] * adv[2] + acc[i][3][r] * adv[3];
#pragma unroll
                for (int off = 8; off > 0; off >>= 1) {
                    sa += __shfl_xor(sa, off, 64);
                    sd += __shfl_xor(sd, off, 64);
                }
                if (l16 == 0 && gr < M) {
                    int h = n0 >> 6;
                    al[gr * H + h] = sa;
                    ar[gr * H + h] = sd;
                }
            } else {
                float saA = acc[i][0][r] * asv[0] + acc[i][1][r] * asv[1];
                float saB = acc[i][2][r] * asv[2] + acc[i][3][r] * asv[3];
                float sdA = acc[i][0][r] * adv[0] + acc[i][1][r] * adv[1];
                float sdB = acc[i][2][r] * adv[2] + acc[i][3][r] * adv[3];
#pragma unroll
                for (int off = 8; off > 0; off >>= 1) {
                    saA += __shfl_xor(saA, off, 64);
                    saB += __shfl_xor(saB, off, 64);
                    sdA += __shfl_xor(sdA, off, 64);
                    sdB += __shfl_xor(sdB, off, 64);
                }
                if (l16 == 0 && gr < M) {
                    int h = n0 >> 5;
                    al[gr * H + h]     = saA;
                    ar[gr * H + h]     = sdA;
                    al[gr * H + h + 1] = saB;
                    ar[gr * H + h + 1] = sdB;
                }
            }
        }
#pragma unroll
    for (int i = 0; i < 2; i++)
#pragma unroll
        for (int j = 0; j < 4; j++)
#pragma unroll
            for (int r = 0; r < 4; r++) {
                int gr = m0 + i * 16 + quad * 4 + r;
                if (gr < M) Cm[(size_t)gr * Nc + n0 + j * 16 + l16] = f2bf(acc[i][j][r]);
            }
}

// ---------------------------------------------------------------------------
// agg v8: softmax fused. Wave per (node, 128-ch group); group owns heads
// [group*HPG, group*HPG+HPG) — partition, no duplicated exp work.
// Pass 1: lanes over edges (idx from preloaded regs), al gather (contig
// HPG floats), p -> wave LDS, per-head s reduce -> inv (folded into one
// end multiply). Pass 2: depth-2 pipelined 16B gathers, alpha from LDS.
// deg>128 tail recomputes p inline (exact).
// ---------------------------------------------------------------------------
template <int HC_, int C, int H>
__global__ __launch_bounds__(256) void gat_agg_fused(
    const bf16_t* __restrict__ hbuf, const float* __restrict__ al,
    const float* __restrict__ ar, const int* __restrict__ rowptr,
    const int* __restrict__ esrc, const float* __restrict__ bias,
    bf16_t* __restrict__ outb, int n, int nodeblocks) {
    constexpr int HPG = 128 / C;                 // heads per group
    __shared__ float plds[4][128 * HPG];
    int group = blockIdx.x / nodeblocks;
    int nb    = blockIdx.x - group * nodeblocks;
    int wv    = threadIdx.x >> 6;
    int node  = nb * 4 + wv;
    if (node >= n) return;
    int lane  = threadIdx.x & 63;
    int ghead = group * HPG;

    int beg = rowptr[node], end = rowptr[node + 1];
    int deg = end - beg;

    // preload first min(deg,128) edge indices, coalesced
    int e0 = 0, e1 = 0;
    {
        int i0 = beg + lane;
        if (i0 < end) e0 = esrc[i0];
        int i1 = beg + 64 + lane;
        if (i1 < end) e1 = esrc[i1];
    }

    // ---- pass 1: scores -> p (LDS), per-head sums ----
    float arv[HPG];
#pragma unroll
    for (int t = 0; t < HPG; t++) arv[t] = ar[(size_t)node * H + ghead + t];
    float s[HPG];
#pragma unroll
    for (int t = 0; t < HPG; t++) s[t] = 0.f;
    float* pw = plds[wv];
    for (int k = 0; k < deg; k += 64) {
        int j = k + lane;
        if (j < deg) {
            int src = (k == 0) ? e0 : ((k == 64) ? e1 : esrc[beg + j]);
            const float* alr = al + (size_t)src * H + ghead;
            float p[HPG];
#pragma unroll
            for (int t = 0; t < HPG; t++) {
                float e = alr[t] + arv[t];
                e = fmaxf(e, 0.2f * e);
                p[t] = __expf(fminf(e, 60.f));
                s[t] += p[t];
            }
            if (j < 128) {
#pragma unroll
                for (int t = 0; t < HPG; t++) pw[j * HPG + t] = p[t];
            }
        }
    }
#pragma unroll
    for (int t = 0; t < HPG; t++) {
        float v = s[t];
#pragma unroll
        for (int off = 32; off > 0; off >>= 1) v += __shfl_xor(v, off, 64);
        s[t] = 1.f / v;
    }

    // ---- pass 2: channel accumulation ----
    int sub = lane >> 4, cl = lane & 15;
    int gc  = group * 128 + cl * 8;
    int t_local = (cl * 8) / C;                  // head-within-group (0..HPG-1)
    float inv_local, arv_local;
    if (HPG == 2) {
        inv_local = t_local ? s[1] : s[0];
        arv_local = t_local ? arv[1] : arv[0];
    } else {
        float iv0 = t_local & 1 ? s[1] : s[0];
        float iv1 = t_local & 1 ? s[3] : s[2];
        inv_local = (t_local & 2) ? iv1 : iv0;
        float av0 = t_local & 1 ? arv[1] : arv[0];
        float av1 = t_local & 1 ? arv[3] : arv[2];
        arv_local = (t_local & 2) ? av1 : av0;
    }
    const bf16_t* hb = hbuf + gc;

    f32x2 acc2[4];
    f32x2 z2 = {0.f, 0.f};
#pragma unroll
    for (int i = 0; i < 4; i++) acc2[i] = z2;

    int npre  = deg < 128 ? deg : 128;
    int nfull = npre >> 3;

    if (nfull > 0) {
        int s0 = __shfl(e0, sub, 64);
        int s1 = __shfl(e0, sub + 4, 64);
        float a0 = pw[sub * HPG + t_local];
        float a1 = pw[(sub + 4) * HPG + t_local];
        bf16x8 u0 = *(const bf16x8*)(hb + (size_t)s0 * HC_);
        bf16x8 u1 = *(const bf16x8*)(hb + (size_t)s1 * HC_);
        for (int it = 1; it < nfull; ++it) {
            int kb = it * 8;
            int esel = (kb < 64) ? e0 : e1;
            int t0 = __shfl(esel, (kb + sub) & 63, 64);
            int t1 = __shfl(esel, (kb + sub + 4) & 63, 64);
            float b0v = pw[(kb + sub) * HPG + t_local];
            float b1v = pw[(kb + sub + 4) * HPG + t_local];
            bf16x8 v0 = *(const bf16x8*)(hb + (size_t)t0 * HC_);
            bf16x8 v1 = *(const bf16x8*)(hb + (size_t)t1 * HC_);
            const unsigned int* d0 = (const unsigned int*)&u0;
            const unsigned int* d1 = (const unsigned int*)&u1;
            f32x2 a0v = {a0, a0}, a1v = {a1, a1};
#pragma unroll
            for (int i = 0; i < 4; i++) {
                f32x2 w0 = {u2f(d0[i] << 16), u2f(d0[i] & 0xffff0000u)};
                f32x2 w1 = {u2f(d1[i] << 16), u2f(d1[i] & 0xffff0000u)};
                acc2[i] += a0v * w0;
                acc2[i] += a1v * w1;
            }
            u0 = v0; u1 = v1; a0 = b0v; a1 = b1v;
        }
        const unsigned int* d0 = (const unsigned int*)&u0;
        const unsigned int* d1 = (const unsigned int*)&u1;
        f32x2 a0v = {a0, a0}, a1v = {a1, a1};
#pragma unroll
        for (int i = 0; i < 4; i++) {
            f32x2 w0 = {u2f(d0[i] << 16), u2f(d0[i] & 0xffff0000u)};
            f32x2 w1 = {u2f(d1[i] << 16), u2f(d1[i] & 0xffff0000u)};
            acc2[i] += a0v * w0;
            acc2[i] += a1v * w1;
        }
    }
    // tail: pack remainder + deg>128 overflow, stride 4, guarded
    for (int j = beg + (nfull << 3) + sub; j < end; j += 4) {
        int s0 = esrc[j];
        int jl = j - beg;
        float a0;
        if (jl < 128) {
            a0 = pw[jl * HPG + t_local];
        } else {
            float e = al[(size_t)s0 * H + ghead + t_local] + arv_local;
            e = fmaxf(e, 0.2f * e);
            a0 = __expf(fminf(e, 60.f));
        }
        bf16x8 u0 = *(const bf16x8*)(hb + (size_t)s0 * HC_);
        const unsigned int* d0 = (const unsigned int*)&u0;
        f32x2 a0v = {a0, a0};
#pragma unroll
        for (int i = 0; i < 4; i++) {
            f32x2 w0 = {u2f(d0[i] << 16), u2f(d0[i] & 0xffff0000u)};
            acc2[i] += a0v * w0;
        }
    }
    float acc[8] = {acc2[0].x, acc2[0].y, acc2[1].x, acc2[1].y,
                    acc2[2].x, acc2[2].y, acc2[3].x, acc2[3].y};
#pragma unroll
    for (int i = 0; i < 8; i++) {
        acc[i] += __shfl_xor(acc[i], 16, 64);
        acc[i] += __shfl_xor(acc[i], 32, 64);
    }
    if (sub == 0) {
        float4 b0 = *(const float4*)(bias + gc);
        float4 b1 = *(const float4*)(bias + gc + 4);
        float bb[8] = {b0.x, b0.y, b0.z, b0.w, b1.x, b1.y, b1.z, b1.w};
        bf16x8 outv;
        unsigned short* ov = (unsigned short*)&outv;
#pragma unroll
        for (int i = 0; i < 8; i++) ov[i] = f2bf(fmaxf(acc[i] * inv_local + bb[i], 0.f));
        *(bf16x8*)(outb + (size_t)node * HC_ + gc) = outv;
    }
}

// ---------------------------------------------------------------------------
// Fused head: out1 = sigmoid(concat(x1,x2,x3).Wf + bf); then MLP -> out2.
// ---------------------------------------------------------------------------
__global__ __launch_bounds__(256) void head_fused(
    const float* __restrict__ x, const bf16_t* __restrict__ x1b,
    const bf16_t* __restrict__ x2b, const bf16_t* __restrict__ x3b,
    const float* __restrict__ Wf, const float* __restrict__ bfc,
    const float* __restrict__ M1w, const float* __restrict__ M1b,
    const float* __restrict__ M2w, const float* __restrict__ M2b,
    const float* __restrict__ M3w, const float* __restrict__ M3b,
    float* __restrict__ out1, float* __restrict__ out2, int n) {
    __shared__ float h1s[4][128];
    int w    = threadIdx.x >> 6;
    int lane = threadIdx.x & 63;
    int node = blockIdx.x * 4 + w;
    bool valid = node < n;
    int nd = valid ? node : 0;

    float s = 0.f;
    {
        ushort4 u = *(const ushort4*)(x1b + (size_t)nd * 256 + lane * 4);
        const float* wv = Wf + lane * 4;
        s += bf2f(u.x) * wv[0] + bf2f(u.y) * wv[1] + bf2f(u.z) * wv[2] + bf2f(u.w) * wv[3];
    }
    {
        ushort4 u = *(const ushort4*)(x2b + (size_t)nd * 256 + lane * 4);
        const float* wv = Wf + 256 + lane * 4;
        s += bf2f(u.x) * wv[0] + bf2f(u.y) * wv[1] + bf2f(u.z) * wv[2] + bf2f(u.w) * wv[3];
    }
#pragma unroll
    for (int i = 0; i < 3; i++) {
        int k = i * 256 + lane * 4;
        ushort4 u = *(const ushort4*)(x3b + (size_t)nd * 768 + k);
        const float* wv = Wf + 512 + k;
        s += bf2f(u.x) * wv[0] + bf2f(u.y) * wv[1] + bf2f(u.z) * wv[2] + bf2f(u.w) * wv[3];
    }
#pragma unroll
    for (int off = 32; off > 0; off >>= 1) s += __shfl_xor(s, off, 64);
    float so = 1.f / (1.f + __expf(-(s + bfc[0])));
    if (lane == 0 && valid) out1[node] = so;

    float xm[17];
#pragma unroll
    for (int k = 0; k < 16; k++) xm[k] = x[nd * 16 + k];
    xm[16] = so;

    float a0 = M1b[lane], a1 = M1b[lane + 64];
#pragma unroll
    for (int k = 0; k < 17; k++) {
        a0 += xm[k] * M1w[k * 128 + lane];
        a1 += xm[k] * M1w[k * 128 + lane + 64];
    }
    h1s[w][lane]      = fmaxf(a0, 0.f);
    h1s[w][lane + 64] = fmaxf(a1, 0.f);
    __syncthreads();

    float b0 = M2b[lane];
#pragma unroll 16
    for (int k = 0; k < 128; k++) b0 += h1s[w][k] * M2w[k * 64 + lane];
    b0 = fmaxf(b0, 0.f);

    float p = b0 * M3w[lane];
#pragma unroll
    for (int off = 32; off > 0; off >>= 1) p += __shfl_xor(p, off, 64);
    if (lane == 0 && valid) out2[node] = 1.f / (1.f + __expf(-(p + M3b[0])));
}

// ---------------------------------------------------------------------------
extern "C" void kernel_launch(void* const* d_in, const int* in_sizes, int n_in,
                              void* d_out, int out_size, void* d_ws, size_t ws_size,
                              hipStream_t stream) {
    const float* x   = (const float*)d_in[0];
    const int*   ei  = (const int*)d_in[1];
    const float* W1  = (const float*)d_in[3];
    const float* a1s = (const float*)d_in[4];
    const float* a1d = (const float*)d_in[5];
    const float* b1  = (const float*)d_in[6];
    const float* W2  = (const float*)d_in[7];
    const float* a2s = (const float*)d_in[8];
    const float* a2d = (const float*)d_in[9];
    const float* b2  = (const float*)d_in[10];
    const float* W3  = (const float*)d_in[11];
    const float* a3s = (const float*)d_in[12];
    const float* a3d = (const float*)d_in[13];
    const float* b3  = (const float*)d_in[14];
    const float* Wf  = (const float*)d_in[15];
    const float* bf  = (const float*)d_in[16];
    const float* M1w = (const float*)d_in[17];
    const float* M1b = (const float*)d_in[18];
    const float* M2w = (const float*)d_in[19];
    const float* M2b = (const float*)d_in[20];
    const float* M3w = (const float*)d_in[21];
    const float* M3b = (const float*)d_in[22];

    const int N = in_sizes[0] / 16;        // 10000
    const int E = in_sizes[1] / 2;         // 320000
    const int Etot = E + N;

    char* base = (char*)d_ws;
    size_t off = 0;
    auto carve = [&](size_t bytes) {
        char* p = base + off;
        off = (off + bytes + 255) & ~(size_t)255;
        return p;
    };
    bf16_t* hbuf   = (bf16_t*)carve((size_t)N * 768 * 2);
    bf16_t* x1b    = (bf16_t*)carve((size_t)N * 256 * 2);
    bf16_t* x2b    = (bf16_t*)carve((size_t)N * 256 * 2);
    bf16_t* x3b    = (bf16_t*)carve((size_t)N * 768 * 2);
    bf16_t* Wt2    = (bf16_t*)carve((size_t)256 * 256 * 2);
    bf16_t* Wt3    = (bf16_t*)carve((size_t)256 * 768 * 2);
    float*  al     = (float*)carve((size_t)N * 12 * 4);
    float*  ar     = (float*)carve((size_t)N * 12 * 4);
    int*    rowptr = (int*)carve((size_t)(N + 1) * 4);
    int*    cnt2   = (int*)carve((size_t)(2 * N) * 4);   // counts | cursor contiguous
    int*    counts = cnt2;
    int*    cursor = cnt2 + N;
    int*    esrc   = (int*)carve((size_t)Etot * 4);
    (void)ws_size;

    float* out1 = (float*)d_out;
    float* out2 = (float*)d_out + N;

    const int TB = 256;
    int eb = (Etot + TB - 1) / TB;
    int nodeblocks = (N + 3) / 4;          // 4 node-waves per block

    // --- CSR by dst + weight prep ---
    hipMemsetAsync(cnt2, 0, (size_t)(2 * N) * 4, stream);
    count_edges<<<eb, TB, 0, stream>>>(ei, E, N, counts);
    scan_rowptr<<<1, 1024, 0, stream>>>(counts, rowptr, N);
    fill_edges<<<eb, TB, 0, stream>>>(ei, E, N, rowptr, cursor, esrc);
    transpose_cast2<<<dim3(16, 64), TB, 0, stream>>>(W2, Wt2, W3, Wt3);

    // --- layer 1: 16 -> 8x32 (fp32 gemm + fused scores; fused-softmax agg) ---
    gemm_f32_sc<<<dim3(4, (N + 63) / 64), TB, 0, stream>>>(x, W1, hbuf, a1s, a1d, al, ar, N, 16, 256, 8);
    gat_agg_fused<256, 32, 8><<<2 * nodeblocks, TB, 0, stream>>>(hbuf, al, ar, rowptr, esrc, b1, x1b, N, nodeblocks);

    // --- layer 2: 256 -> 8x32 (MFMA + fused scores; fused-softmax agg) ---
    gemm_mfma_sc<32><<<dim3(4, (N + 127) / 128), TB, 0, stream>>>(x1b, Wt2, hbuf, a2s, a2d, al, ar, N, 256, 256, 8);
    gat_agg_fused<256, 32, 8><<<2 * nodeblocks, TB, 0, stream>>>(hbuf, al, ar, rowptr, esrc, b2, x2b, N, nodeblocks);

    // --- layer 3: 256 -> 12x64 (MFMA + fused scores; fused-softmax agg) ---
    gemm_mfma_sc<64><<<dim3(12, (N + 127) / 128), TB, 0, stream>>>(x2b, Wt3, hbuf, a3s, a3d, al, ar, N, 256, 768, 12);
    gat_agg_fused<768, 64, 12><<<6 * nodeblocks, TB, 0, stream>>>(hbuf, al, ar, rowptr, esrc, b3, x3b, N, nodeblocks);

    // --- fused final linear + MLP ---
    head_fused<<<nodeblocks, TB, 0, stream>>>(x, x1b, x2b, x3b, Wf, bf,
                                              M1w, M1b, M2w, M2b, M3w, M3b, out1, out2, N);
}

// Round 14
// 309.380 us; speedup vs baseline: 1.1665x; 1.0107x over previous
//
#include <hip/hip_runtime.h>
#include <math.h>

// ---------------------------------------------------------------------------
// GATNet (3x GATConv + final linear + MLP), MI355X.
// R13: tail-free agg packing — pack count rounded UP, LDS p zero-padded for
// [deg, 8*nfull); OOB lanes gather row 0 with alpha=0 (exact, branchless).
// Removes the latency-exposed 1-7-edge guarded tail from every wave.
// Carried: fused-score GEMMs, fused-softmax agg, pk-fma, preloaded indices.
// ---------------------------------------------------------------------------

typedef unsigned short bf16_t;
typedef __attribute__((ext_vector_type(8))) short bf16x8;
typedef __attribute__((ext_vector_type(4))) float f32x4;
typedef __attribute__((ext_vector_type(2))) float f32x2;

__device__ inline float bf2f(bf16_t u) {
    union { unsigned int i; float f; } v; v.i = ((unsigned int)u) << 16; return v.f;
}
__device__ inline float u2f(unsigned int x) {
    union { unsigned int i; float f; } v; v.i = x; return v.f;
}
__device__ inline bf16_t f2bf(float f) {
    union { float f; unsigned int i; } v; v.f = f;
    unsigned int r = v.i + 0x7FFF + ((v.i >> 16) & 1);   // round-nearest-even
    return (bf16_t)(r >> 16);
}

// ------------------------------ CSR build ----------------------------------

__global__ void count_edges(const int* __restrict__ ei, int E, int Nn,
                            int* __restrict__ counts) {
    int e = blockIdx.x * blockDim.x + threadIdx.x;
    if (e >= E + Nn) return;
    int dst = (e < E) ? ei[E + e] : (e - E);   // self-loops appended
    atomicAdd(&counts[dst], 1);
}

// single block, 1024 threads: serial-per-thread + shuffle block scan
__global__ __launch_bounds__(1024) void scan_rowptr(const int* __restrict__ counts,
                                                    int* __restrict__ rowptr, int n) {
    const int IPT = (n + 1023) / 1024;   // <=16
    int t = threadIdx.x;
    int base = t * IPT;
    int loc[16];
    int run = 0;
#pragma unroll
    for (int i = 0; i < 16; i++) {
        if (i >= IPT) break;
        int idx = base + i;
        int v = (idx < n) ? counts[idx] : 0;
        loc[i] = run;
        run += v;
    }
    int lane = t & 63, wid = t >> 6;
    int v = run;
    for (int off = 1; off < 64; off <<= 1) {
        int u = __shfl_up(v, off, 64);
        if (lane >= off) v += u;
    }
    __shared__ int wsum[16];
    __shared__ int woff[16];
    if (lane == 63) wsum[wid] = v;
    __syncthreads();
    if (t == 0) { int s = 0; for (int i = 0; i < 16; i++) { woff[i] = s; s += wsum[i]; } }
    __syncthreads();
    int excl = v - run + woff[wid];
#pragma unroll
    for (int i = 0; i < 16; i++) {
        if (i >= IPT) break;
        int idx = base + i;
        if (idx < n) rowptr[idx] = excl + loc[i];
    }
    if (t == 1023) rowptr[n] = excl + run;
}

__global__ void fill_edges(const int* __restrict__ ei, int E, int Nn,
                           const int* __restrict__ rowptr, int* __restrict__ cursor,
                           int* __restrict__ edge_src) {
    int e = blockIdx.x * blockDim.x + threadIdx.x;
    if (e >= E + Nn) return;
    int src, dst;
    if (e < E) { src = ei[e]; dst = ei[E + e]; }
    else       { src = e - E; dst = src; }
    int pos = atomicAdd(&cursor[dst], 1);
    edge_src[rowptr[dst] + pos] = src;
}

// ---------------------------------------------------------------------------
// Fused transpose+cast for both weight matrices (K=256 each).
// ---------------------------------------------------------------------------
__global__ __launch_bounds__(256) void transpose_cast2(const float* __restrict__ W2,
                                                       bf16_t* __restrict__ Wt2,
                                                       const float* __restrict__ W3,
                                                       bf16_t* __restrict__ Wt3) {
    __shared__ float tile[16][17];
    const float* W; bf16_t* Wt; int Nc, n0;
    if (blockIdx.y < 16) { W = W2; Wt = Wt2; Nc = 256; n0 = blockIdx.y * 16; }
    else                 { W = W3; Wt = Wt3; Nc = 768; n0 = (blockIdx.y - 16) * 16; }
    int k0 = blockIdx.x * 16;
    int tx = threadIdx.x & 15, ty = threadIdx.x >> 4;
    tile[ty][tx] = W[(size_t)(k0 + ty) * Nc + n0 + tx];
    __syncthreads();
    Wt[(size_t)(n0 + ty) * 256 + k0 + tx] = f2bf(tile[tx][ty]);
}

// ---------------------------------------------------------------------------
// fp32 GEMM (layer 1, K=16, C=32, H=8), bf16 out + fused al/ar scores.
// ---------------------------------------------------------------------------
__global__ __launch_bounds__(256) void gemm_f32_sc(const float* __restrict__ A,
                                                   const float* __restrict__ B,
                                                   bf16_t* __restrict__ Cm,
                                                   const float* __restrict__ a_s,
                                                   const float* __restrict__ a_d,
                                                   float* __restrict__ al,
                                                   float* __restrict__ ar,
                                                   int M, int K, int Nc, int H) {
    __shared__ float As[16][64];
    __shared__ float Bs[16][64];
    int t  = threadIdx.x;
    int tx = t & 15, ty = t >> 4;
    int row0 = blockIdx.y * 64, col0 = blockIdx.x * 64;
    int a_r = t >> 2, a_c = (t & 3) * 4;
    int b_r = t >> 4, b_c = (t & 15) * 4;

    float acc[4][4];
#pragma unroll
    for (int i = 0; i < 4; i++)
#pragma unroll
        for (int j = 0; j < 4; j++) acc[i][j] = 0.f;

    for (int kt = 0; kt < K; kt += 16) {
        float4 av = make_float4(0.f, 0.f, 0.f, 0.f);
        int gr = row0 + a_r;
        if (gr < M) av = *(const float4*)(A + (size_t)gr * K + kt + a_c);
        As[a_c + 0][a_r] = av.x;
        As[a_c + 1][a_r] = av.y;
        As[a_c + 2][a_r] = av.z;
        As[a_c + 3][a_r] = av.w;
        float4 bv = *(const float4*)(B + (size_t)(kt + b_r) * Nc + col0 + b_c);
        *(float4*)&Bs[b_r][b_c] = bv;
        __syncthreads();
#pragma unroll
        for (int k = 0; k < 16; k++) {
            float4 a4 = *(const float4*)&As[k][ty * 4];
            float4 b4 = *(const float4*)&Bs[k][tx * 4];
            float aa[4] = {a4.x, a4.y, a4.z, a4.w};
            float bb[4] = {b4.x, b4.y, b4.z, b4.w};
#pragma unroll
            for (int i = 0; i < 4; i++)
#pragma unroll
                for (int j = 0; j < 4; j++) acc[i][j] += aa[i] * bb[j];
        }
        __syncthreads();
    }
    float4 asv = *(const float4*)(a_s + col0 + tx * 4);
    float4 adv = *(const float4*)(a_d + col0 + tx * 4);
#pragma unroll
    for (int i = 0; i < 4; i++) {
        int gr = row0 + ty * 4 + i;
        float sa = acc[i][0] * asv.x + acc[i][1] * asv.y + acc[i][2] * asv.z + acc[i][3] * asv.w;
        float sd = acc[i][0] * adv.x + acc[i][1] * adv.y + acc[i][2] * adv.z + acc[i][3] * adv.w;
#pragma unroll
        for (int off = 4; off > 0; off >>= 1) {
            sa += __shfl_xor(sa, off, 64);
            sd += __shfl_xor(sd, off, 64);
        }
        if ((tx == 0 || tx == 8) && gr < M) {
            int h = (col0 >> 5) + (tx >> 3);
            al[gr * H + h] = sa;
            ar[gr * H + h] = sd;
        }
        if (gr < M) {
            ushort4 v;
            v.x = f2bf(acc[i][0]); v.y = f2bf(acc[i][1]);
            v.z = f2bf(acc[i][2]); v.w = f2bf(acc[i][3]);
            *(ushort4*)(Cm + (size_t)gr * Nc + col0 + tx * 4) = v;
        }
    }
}

// ---------------------------------------------------------------------------
// MFMA bf16 GEMM (layers 2/3) + fused al/ar scores (block-local, no atomics).
// ---------------------------------------------------------------------------
template <int C_>
__global__ __launch_bounds__(256) void gemm_mfma_sc(const bf16_t* __restrict__ A,
                                                    const bf16_t* __restrict__ Bt,
                                                    bf16_t* __restrict__ Cm,
                                                    const float* __restrict__ a_s,
                                                    const float* __restrict__ a_d,
                                                    float* __restrict__ al,
                                                    float* __restrict__ ar,
                                                    int M, int K, int Nc, int H) {
    int wave = threadIdx.x >> 6, lane = threadIdx.x & 63;
    int quad = lane >> 4, l16 = lane & 15;
    int m0 = blockIdx.y * 128 + wave * 32;
    int n0 = blockIdx.x * 64;

    f32x4 acc[2][4];
    f32x4 z = {0.f, 0.f, 0.f, 0.f};
#pragma unroll
    for (int i = 0; i < 2; i++)
#pragma unroll
        for (int j = 0; j < 4; j++) acc[i][j] = z;

    int r0 = m0 + l16;       if (r0 >= M) r0 = M - 1;
    int r1 = m0 + 16 + l16;  if (r1 >= M) r1 = M - 1;
    const bf16_t* Ap0 = A + (size_t)r0 * K + quad * 8;
    const bf16_t* Ap1 = A + (size_t)r1 * K + quad * 8;
    const bf16_t* Bp0 = Bt + (size_t)(n0 + 0  + l16) * K + quad * 8;
    const bf16_t* Bp1 = Bt + (size_t)(n0 + 16 + l16) * K + quad * 8;
    const bf16_t* Bp2 = Bt + (size_t)(n0 + 32 + l16) * K + quad * 8;
    const bf16_t* Bp3 = Bt + (size_t)(n0 + 48 + l16) * K + quad * 8;

    for (int kt = 0; kt < K; kt += 32) {
        bf16x8 a0 = *(const bf16x8*)(Ap0 + kt);
        bf16x8 a1 = *(const bf16x8*)(Ap1 + kt);
        bf16x8 b0 = *(const bf16x8*)(Bp0 + kt);
        bf16x8 b1 = *(const bf16x8*)(Bp1 + kt);
        bf16x8 b2 = *(const bf16x8*)(Bp2 + kt);
        bf16x8 b3 = *(const bf16x8*)(Bp3 + kt);
        acc[0][0] = __builtin_amdgcn_mfma_f32_16x16x32_bf16(a0, b0, acc[0][0], 0, 0, 0);
        acc[1][0] = __builtin_amdgcn_mfma_f32_16x16x32_bf16(a1, b0, acc[1][0], 0, 0, 0);
        acc[0][1] = __builtin_amdgcn_mfma_f32_16x16x32_bf16(a0, b1, acc[0][1], 0, 0, 0);
        acc[1][1] = __builtin_amdgcn_mfma_f32_16x16x32_bf16(a1, b1, acc[1][1], 0, 0, 0);
        acc[0][2] = __builtin_amdgcn_mfma_f32_16x16x32_bf16(a0, b2, acc[0][2], 0, 0, 0);
        acc[1][2] = __builtin_amdgcn_mfma_f32_16x16x32_bf16(a1, b2, acc[1][2], 0, 0, 0);
        acc[0][3] = __builtin_amdgcn_mfma_f32_16x16x32_bf16(a0, b3, acc[0][3], 0, 0, 0);
        acc[1][3] = __builtin_amdgcn_mfma_f32_16x16x32_bf16(a1, b3, acc[1][3], 0, 0, 0);
    }

    float asv[4], adv[4];
#pragma unroll
    for (int j = 0; j < 4; j++) {
        asv[j] = a_s[n0 + j * 16 + l16];
        adv[j] = a_d[n0 + j * 16 + l16];
    }
#pragma unroll
    for (int i = 0; i < 2; i++)
#pragma unroll
        for (int r = 0; r < 4; r++) {
            int gr = m0 + i * 16 + quad * 4 + r;
            if (C_ == 64) {
                float sa = acc[i][0][r] * asv[0] + acc[i][1][r] * asv[1]
                         + acc[i][2][r] * asv[2] + acc[i][3][r] * asv[3];
                float sd = acc[i][0][r] * adv[0] + acc[i][1][r] * adv[1]
                         + acc[i][2][r] * adv[2] + acc[i][3][r] * adv[3];
#pragma unroll
                for (int off = 8; off > 0; off >>= 1) {
                    sa += __shfl_xor(sa, off, 64);
                    sd += __shfl_xor(sd, off, 64);
                }
                if (l16 == 0 && gr < M) {
                    int h = n0 >> 6;
                    al[gr * H + h] = sa;
                    ar[gr * H + h] = sd;
                }
            } else {
                float saA = acc[i][0][r] * asv[0] + acc[i][1][r] * asv[1];
                float saB = acc[i][2][r] * asv[2] + acc[i][3][r] * asv[3];
                float sdA = acc[i][0][r] * adv[0] + acc[i][1][r] * adv[1];
                float sdB = acc[i][2][r] * adv[2] + acc[i][3][r] * adv[3];
#pragma unroll
                for (int off = 8; off > 0; off >>= 1) {
                    saA += __shfl_xor(saA, off, 64);
                    saB += __shfl_xor(saB, off, 64);
                    sdA += __shfl_xor(sdA, off, 64);
                    sdB += __shfl_xor(sdB, off, 64);
                }
                if (l16 == 0 && gr < M) {
                    int h = n0 >> 5;
                    al[gr * H + h]     = saA;
                    ar[gr * H + h]     = sdA;
                    al[gr * H + h + 1] = saB;
                    ar[gr * H + h + 1] = sdB;
                }
            }
        }
#pragma unroll
    for (int i = 0; i < 2; i++)
#pragma unroll
        for (int j = 0; j < 4; j++)
#pragma unroll
            for (int r = 0; r < 4; r++) {
                int gr = m0 + i * 16 + quad * 4 + r;
                if (gr < M) Cm[(size_t)gr * Nc + n0 + j * 16 + l16] = f2bf(acc[i][j][r]);
            }
}

// ---------------------------------------------------------------------------
// agg v9: fused softmax + TAIL-FREE packing. Pack count rounded up; LDS p
// zero-padded over [deg, 8*nfull) so OOB pack lanes gather row 0 (e-regs
// default 0 -> valid addr) weighted by alpha=0. Guarded tail only deg>128.
// ---------------------------------------------------------------------------
template <int HC_, int C, int H>
__global__ __launch_bounds__(256) void gat_agg_fused(
    const bf16_t* __restrict__ hbuf, const float* __restrict__ al,
    const float* __restrict__ ar, const int* __restrict__ rowptr,
    const int* __restrict__ esrc, const float* __restrict__ bias,
    bf16_t* __restrict__ outb, int n, int nodeblocks) {
    constexpr int HPG = 128 / C;                 // heads per group
    __shared__ float plds[4][128 * HPG];
    int group = blockIdx.x / nodeblocks;
    int nb    = blockIdx.x - group * nodeblocks;
    int wv    = threadIdx.x >> 6;
    int node  = nb * 4 + wv;
    if (node >= n) return;
    int lane  = threadIdx.x & 63;
    int ghead = group * HPG;

    int beg = rowptr[node], end = rowptr[node + 1];
    int deg = end - beg;

    // preload first min(deg,128) edge indices, coalesced (default 0 = valid row)
    int e0 = 0, e1 = 0;
    {
        int i0 = beg + lane;
        if (i0 < end) e0 = esrc[i0];
        int i1 = beg + 64 + lane;
        if (i1 < end) e1 = esrc[i1];
    }
    int npre  = deg < 128 ? deg : 128;
    int nfull = (npre + 7) >> 3;                 // rounded UP — no short tail

    // ---- pass 1: scores -> p (LDS), per-head sums; zero-pad [deg, 8*nfull) ----
    float arv[HPG];
#pragma unroll
    for (int t = 0; t < HPG; t++) arv[t] = ar[(size_t)node * H + ghead + t];
    float s[HPG];
#pragma unroll
    for (int t = 0; t < HPG; t++) s[t] = 0.f;
    float* pw = plds[wv];
    {
        int jz = deg + lane;
        if (jz < (nfull << 3)) {
#pragma unroll
            for (int t = 0; t < HPG; t++) pw[jz * HPG + t] = 0.f;
        }
    }
    for (int k = 0; k < deg; k += 64) {
        int j = k + lane;
        if (j < deg) {
            int src = (k == 0) ? e0 : ((k == 64) ? e1 : esrc[beg + j]);
            const float* alr = al + (size_t)src * H + ghead;
            float p[HPG];
#pragma unroll
            for (int t = 0; t < HPG; t++) {
                float e = alr[t] + arv[t];
                e = fmaxf(e, 0.2f * e);
                p[t] = __expf(fminf(e, 60.f));
                s[t] += p[t];
            }
            if (j < 128) {
#pragma unroll
                for (int t = 0; t < HPG; t++) pw[j * HPG + t] = p[t];
            }
        }
    }
#pragma unroll
    for (int t = 0; t < HPG; t++) {
        float v = s[t];
#pragma unroll
        for (int off = 32; off > 0; off >>= 1) v += __shfl_xor(v, off, 64);
        s[t] = 1.f / v;
    }

    // ---- pass 2: channel accumulation ----
    int sub = lane >> 4, cl = lane & 15;
    int gc  = group * 128 + cl * 8;
    int t_local = (cl * 8) / C;                  // head-within-group
    float inv_local, arv_local;
    if (HPG == 2) {
        inv_local = t_local ? s[1] : s[0];
        arv_local = t_local ? arv[1] : arv[0];
    } else {
        float iv0 = t_local & 1 ? s[1] : s[0];
        float iv1 = t_local & 1 ? s[3] : s[2];
        inv_local = (t_local & 2) ? iv1 : iv0;
        float av0 = t_local & 1 ? arv[1] : arv[0];
        float av1 = t_local & 1 ? arv[3] : arv[2];
        arv_local = (t_local & 2) ? av1 : av0;
    }
    const bf16_t* hb = hbuf + gc;

    f32x2 acc2[4];
    f32x2 z2 = {0.f, 0.f};
#pragma unroll
    for (int i = 0; i < 4; i++) acc2[i] = z2;

    if (nfull > 0) {
        int s0 = __shfl(e0, sub, 64);
        int s1 = __shfl(e0, sub + 4, 64);
        float a0 = pw[sub * HPG + t_local];
        float a1 = pw[(sub + 4) * HPG + t_local];
        bf16x8 u0 = *(const bf16x8*)(hb + (size_t)s0 * HC_);
        bf16x8 u1 = *(const bf16x8*)(hb + (size_t)s1 * HC_);
        for (int it = 1; it < nfull; ++it) {
            int kb = it * 8;
            int esel = (kb < 64) ? e0 : e1;
            int t0 = __shfl(esel, (kb + sub) & 63, 64);
            int t1 = __shfl(esel, (kb + sub + 4) & 63, 64);
            float b0v = pw[(kb + sub) * HPG + t_local];
            float b1v = pw[(kb + sub + 4) * HPG + t_local];
            bf16x8 v0 = *(const bf16x8*)(hb + (size_t)t0 * HC_);
            bf16x8 v1 = *(const bf16x8*)(hb + (size_t)t1 * HC_);
            const unsigned int* d0 = (const unsigned int*)&u0;
            const unsigned int* d1 = (const unsigned int*)&u1;
            f32x2 a0v = {a0, a0}, a1v = {a1, a1};
#pragma unroll
            for (int i = 0; i < 4; i++) {
                f32x2 w0 = {u2f(d0[i] << 16), u2f(d0[i] & 0xffff0000u)};
                f32x2 w1 = {u2f(d1[i] << 16), u2f(d1[i] & 0xffff0000u)};
                acc2[i] += a0v * w0;
                acc2[i] += a1v * w1;
            }
            u0 = v0; u1 = v1; a0 = b0v; a1 = b1v;
        }
        const unsigned int* d0 = (const unsigned int*)&u0;
        const unsigned int* d1 = (const unsigned int*)&u1;
        f32x2 a0v = {a0, a0}, a1v = {a1, a1};
#pragma unroll
        for (int i = 0; i < 4; i++) {
            f32x2 w0 = {u2f(d0[i] << 16), u2f(d0[i] & 0xffff0000u)};
            f32x2 w1 = {u2f(d1[i] << 16), u2f(d1[i] & 0xffff0000u)};
            acc2[i] += a0v * w0;
            acc2[i] += a1v * w1;
        }
    }
    // tail: only deg>128 overflow (rare), stride 4, recompute p inline
    for (int j = beg + (nfull << 3) + sub; j < end; j += 4) {
        int s0 = esrc[j];
        float e = al[(size_t)s0 * H + ghead + t_local] + arv_local;
        e = fmaxf(e, 0.2f * e);
        float a0 = __expf(fminf(e, 60.f));
        bf16x8 u0 = *(const bf16x8*)(hb + (size_t)s0 * HC_);
        const unsigned int* d0 = (const unsigned int*)&u0;
        f32x2 a0v = {a0, a0};
#pragma unroll
        for (int i = 0; i < 4; i++) {
            f32x2 w0 = {u2f(d0[i] << 16), u2f(d0[i] & 0xffff0000u)};
            acc2[i] += a0v * w0;
        }
    }
    float acc[8] = {acc2[0].x, acc2[0].y, acc2[1].x, acc2[1].y,
                    acc2[2].x, acc2[2].y, acc2[3].x, acc2[3].y};
#pragma unroll
    for (int i = 0; i < 8; i++) {
        acc[i] += __shfl_xor(acc[i], 16, 64);
        acc[i] += __shfl_xor(acc[i], 32, 64);
    }
    if (sub == 0) {
        float4 b0 = *(const float4*)(bias + gc);
        float4 b1 = *(const float4*)(bias + gc + 4);
        float bb[8] = {b0.x, b0.y, b0.z, b0.w, b1.x, b1.y, b1.z, b1.w};
        bf16x8 outv;
        unsigned short* ov = (unsigned short*)&outv;
#pragma unroll
        for (int i = 0; i < 8; i++) ov[i] = f2bf(fmaxf(acc[i] * inv_local + bb[i], 0.f));
        *(bf16x8*)(outb + (size_t)node * HC_ + gc) = outv;
    }
}

// ---------------------------------------------------------------------------
// Fused head: out1 = sigmoid(concat(x1,x2,x3).Wf + bf); then MLP -> out2.
// ---------------------------------------------------------------------------
__global__ __launch_bounds__(256) void head_fused(
    const float* __restrict__ x, const bf16_t* __restrict__ x1b,
    const bf16_t* __restrict__ x2b, const bf16_t* __restrict__ x3b,
    const float* __restrict__ Wf, const float* __restrict__ bfc,
    const float* __restrict__ M1w, const float* __restrict__ M1b,
    const float* __restrict__ M2w, const float* __restrict__ M2b,
    const float* __restrict__ M3w, const float* __restrict__ M3b,
    float* __restrict__ out1, float* __restrict__ out2, int n) {
    __shared__ float h1s[4][128];
    int w    = threadIdx.x >> 6;
    int lane = threadIdx.x & 63;
    int node = blockIdx.x * 4 + w;
    bool valid = node < n;
    int nd = valid ? node : 0;

    float s = 0.f;
    {
        ushort4 u = *(const ushort4*)(x1b + (size_t)nd * 256 + lane * 4);
        const float* wv = Wf + lane * 4;
        s += bf2f(u.x) * wv[0] + bf2f(u.y) * wv[1] + bf2f(u.z) * wv[2] + bf2f(u.w) * wv[3];
    }
    {
        ushort4 u = *(const ushort4*)(x2b + (size_t)nd * 256 + lane * 4);
        const float* wv = Wf + 256 + lane * 4;
        s += bf2f(u.x) * wv[0] + bf2f(u.y) * wv[1] + bf2f(u.z) * wv[2] + bf2f(u.w) * wv[3];
    }
#pragma unroll
    for (int i = 0; i < 3; i++) {
        int k = i * 256 + lane * 4;
        ushort4 u = *(const ushort4*)(x3b + (size_t)nd * 768 + k);
        const float* wv = Wf + 512 + k;
        s += bf2f(u.x) * wv[0] + bf2f(u.y) * wv[1] + bf2f(u.z) * wv[2] + bf2f(u.w) * wv[3];
    }
#pragma unroll
    for (int off = 32; off > 0; off >>= 1) s += __shfl_xor(s, off, 64);
    float so = 1.f / (1.f + __expf(-(s + bfc[0])));
    if (lane == 0 && valid) out1[node] = so;

    float xm[17];
#pragma unroll
    for (int k = 0; k < 16; k++) xm[k] = x[nd * 16 + k];
    xm[16] = so;

    float a0 = M1b[lane], a1 = M1b[lane + 64];
#pragma unroll
    for (int k = 0; k < 17; k++) {
        a0 += xm[k] * M1w[k * 128 + lane];
        a1 += xm[k] * M1w[k * 128 + lane + 64];
    }
    h1s[w][lane]      = fmaxf(a0, 0.f);
    h1s[w][lane + 64] = fmaxf(a1, 0.f);
    __syncthreads();

    float b0 = M2b[lane];
#pragma unroll 16
    for (int k = 0; k < 128; k++) b0 += h1s[w][k] * M2w[k * 64 + lane];
    b0 = fmaxf(b0, 0.f);

    float p = b0 * M3w[lane];
#pragma unroll
    for (int off = 32; off > 0; off >>= 1) p += __shfl_xor(p, off, 64);
    if (lane == 0 && valid) out2[node] = 1.f / (1.f + __expf(-(p + M3b[0])));
}

// ---------------------------------------------------------------------------
extern "C" void kernel_launch(void* const* d_in, const int* in_sizes, int n_in,
                              void* d_out, int out_size, void* d_ws, size_t ws_size,
                              hipStream_t stream) {
    const float* x   = (const float*)d_in[0];
    const int*   ei  = (const int*)d_in[1];
    const float* W1  = (const float*)d_in[3];
    const float* a1s = (const float*)d_in[4];
    const float* a1d = (const float*)d_in[5];
    const float* b1  = (const float*)d_in[6];
    const float* W2  = (const float*)d_in[7];
    const float* a2s = (const float*)d_in[8];
    const float* a2d = (const float*)d_in[9];
    const float* b2  = (const float*)d_in[10];
    const float* W3  = (const float*)d_in[11];
    const float* a3s = (const float*)d_in[12];
    const float* a3d = (const float*)d_in[13];
    const float* b3  = (const float*)d_in[14];
    const float* Wf  = (const float*)d_in[15];
    const float* bf  = (const float*)d_in[16];
    const float* M1w = (const float*)d_in[17];
    const float* M1b = (const float*)d_in[18];
    const float* M2w = (const float*)d_in[19];
    const float* M2b = (const float*)d_in[20];
    const float* M3w = (const float*)d_in[21];
    const float* M3b = (const float*)d_in[22];

    const int N = in_sizes[0] / 16;        // 10000
    const int E = in_sizes[1] / 2;         // 320000
    const int Etot = E + N;

    char* base = (char*)d_ws;
    size_t off = 0;
    auto carve = [&](size_t bytes) {
        char* p = base + off;
        off = (off + bytes + 255) & ~(size_t)255;
        return p;
    };
    bf16_t* hbuf   = (bf16_t*)carve((size_t)N * 768 * 2);
    bf16_t* x1b    = (bf16_t*)carve((size_t)N * 256 * 2);
    bf16_t* x2b    = (bf16_t*)carve((size_t)N * 256 * 2);
    bf16_t* x3b    = (bf16_t*)carve((size_t)N * 768 * 2);
    bf16_t* Wt2    = (bf16_t*)carve((size_t)256 * 256 * 2);
    bf16_t* Wt3    = (bf16_t*)carve((size_t)256 * 768 * 2);
    float*  al     = (float*)carve((size_t)N * 12 * 4);
    float*  ar     = (float*)carve((size_t)N * 12 * 4);
    int*    rowptr = (int*)carve((size_t)(N + 1) * 4);
    int*    cnt2   = (int*)carve((size_t)(2 * N) * 4);   // counts | cursor contiguous
    int*    counts = cnt2;
    int*    cursor = cnt2 + N;
    int*    esrc   = (int*)carve((size_t)Etot * 4);
    (void)ws_size;

    float* out1 = (float*)d_out;
    float* out2 = (float*)d_out + N;

    const int TB = 256;
    int eb = (Etot + TB - 1) / TB;
    int nodeblocks = (N + 3) / 4;          // 4 node-waves per block

    // --- CSR by dst + weight prep ---
    hipMemsetAsync(cnt2, 0, (size_t)(2 * N) * 4, stream);
    count_edges<<<eb, TB, 0, stream>>>(ei, E, N, counts);
    scan_rowptr<<<1, 1024, 0, stream>>>(counts, rowptr, N);
    fill_edges<<<eb, TB, 0, stream>>>(ei, E, N, rowptr, cursor, esrc);
    transpose_cast2<<<dim3(16, 64), TB, 0, stream>>>(W2, Wt2, W3, Wt3);

    // --- layer 1: 16 -> 8x32 (fp32 gemm + fused scores; fused-softmax agg) ---
    gemm_f32_sc<<<dim3(4, (N + 63) / 64), TB, 0, stream>>>(x, W1, hbuf, a1s, a1d, al, ar, N, 16, 256, 8);
    gat_agg_fused<256, 32, 8><<<2 * nodeblocks, TB, 0, stream>>>(hbuf, al, ar, rowptr, esrc, b1, x1b, N, nodeblocks);

    // --- layer 2: 256 -> 8x32 (MFMA + fused scores; fused-softmax agg) ---
    gemm_mfma_sc<32><<<dim3(4, (N + 127) / 128), TB, 0, stream>>>(x1b, Wt2, hbuf, a2s, a2d, al, ar, N, 256, 256, 8);
    gat_agg_fused<256, 32, 8><<<2 * nodeblocks, TB, 0, stream>>>(hbuf, al, ar, rowptr, esrc, b2, x2b, N, nodeblocks);

    // --- layer 3: 256 -> 12x64 (MFMA + fused scores; fused-softmax agg) ---
    gemm_mfma_sc<64><<<dim3(12, (N + 127) / 128), TB, 0, stream>>>(x2b, Wt3, hbuf, a3s, a3d, al, ar, N, 256, 768, 12);
    gat_agg_fused<768, 64, 12><<<6 * nodeblocks, TB, 0, stream>>>(hbuf, al, ar, rowptr, esrc, b3, x3b, N, nodeblocks);

    // --- fused final linear + MLP ---
    head_fused<<<nodeblocks, TB, 0, stream>>>(x, x1b, x2b, x3b, Wf, bf,
                                              M1w, M1b, M2w, M2b, M3w, M3b, out1, out2, N);
}